// Round 14
// baseline (1091.798 us; speedup 1.0000x reference)
//
#include <hip/hip_runtime.h>
#include <hip/hip_bf16.h>
#include <math.h>

// Problem constants
#define NN   1024
#define CS   384
#define CZ   128
#define HH   12
#define HCH  192
#define QPR  144
#define DCAT 2112
#define PROJW 1152    // 192+384+144+432
#define INF_ 100000.0f

#define SC_QK 0.14433756729740643f   // sqrt(1/48)
#define SC_B  0.5773502691896258f    // sqrt(1/3)
#define SC_PT 0.13608276348795434f   // sqrt(1/54)

__device__ __forceinline__ float dot4(float4 a, float4 b) {
  return a.x * b.x + a.y * b.y + a.z * b.z + a.w * b.w;
}
__device__ __forceinline__ float bf2f(unsigned short u) {
  unsigned int v = ((unsigned int)u) << 16;
  float f; __builtin_memcpy(&f, &v, 4); return f;
}
__device__ __forceinline__ unsigned short f2bf(float f) {
  __hip_bfloat16 h = __float2bfloat16(f);
  unsigned short u; __builtin_memcpy(&u, &h, 2); return u;
}

// ---------------------------------------------------------------------------
// proj_all: fused s @ {wq,wkv,wqp,wkvp} + bias -> proj[n][1152]
// ---------------------------------------------------------------------------
__global__ __launch_bounds__(256) void proj_all(
    const float* __restrict__ s,
    const float* __restrict__ wq, const float* __restrict__ bq,
    const float* __restrict__ wkv, const float* __restrict__ bkv,
    const float* __restrict__ wqp, const float* __restrict__ bqp,
    const float* __restrict__ wkvp, const float* __restrict__ bkvp,
    float* __restrict__ proj)
{
  __shared__ float s_lds[8 * CS];
  const int n0 = blockIdx.x * 8;
  for (int idx = threadIdx.x; idx < 8 * CS; idx += 256)
    s_lds[idx] = s[(size_t)(n0 + idx / CS) * CS + (idx % CS)];
  __syncthreads();

  const int gc = blockIdx.y * 128 + (threadIdx.x & 31) * 4;
  const int rg = threadIdx.x >> 5;
  const float* wp; const float* bp; int OUT, lc;
  if (gc < 192)      { wp = wq;   bp = bq;   OUT = 192; lc = gc; }
  else if (gc < 576) { wp = wkv;  bp = bkv;  OUT = 384; lc = gc - 192; }
  else if (gc < 720) { wp = wqp;  bp = bqp;  OUT = 144; lc = gc - 576; }
  else               { wp = wkvp; bp = bkvp; OUT = 432; lc = gc - 720; }

  float a0 = 0.f, a1 = 0.f, a2 = 0.f, a3 = 0.f;
  const float* srow = &s_lds[rg * CS];
#pragma unroll 4
  for (int kk = 0; kk < CS; kk++) {
    float sv = srow[kk];
    float4 w4 = *reinterpret_cast<const float4*>(&wp[(size_t)kk * OUT + lc]);
    a0 += sv * w4.x; a1 += sv * w4.y; a2 += sv * w4.z; a3 += sv * w4.w;
  }
  float* o = proj + (size_t)(n0 + rg) * PROJW + gc;
  o[0] = a0 + bp[lc]; o[1] = a1 + bp[lc + 1];
  o[2] = a2 + bp[lc + 2]; o[3] = a3 + bp[lc + 3];
}

// ---------------------------------------------------------------------------
// transform: split kv, rotate/translate points, write COMPONENT-MAJOR layouts
// ---------------------------------------------------------------------------
__global__ __launch_bounds__(256) void ipa_transform(
    const float* __restrict__ proj, const float* __restrict__ rot,
    const float* __restrict__ trans,
    float* __restrict__ kc, float* __restrict__ vc,
    float* __restrict__ q_pts, float* __restrict__ kpc,
    float* __restrict__ vpc, float* __restrict__ qn, float* __restrict__ knc)
{
  const int n = blockIdx.x, tid = threadIdx.x;
  const float* pr = proj + (size_t)n * PROJW;
  __shared__ float R[9], T[3], sq_q[48], sq_k[48];
  if (tid < 9) R[tid] = rot[n * 9 + tid];
  if (tid < 3) T[tid] = trans[n * 3 + tid];
  __syncthreads();
  if (tid < HCH) {
    int h = tid >> 4, c = tid & 15;
    kc[(size_t)(h * 16 + c) * NN + n] = pr[192 + h * 32 + c];
    vc[(size_t)(h * 16 + c) * NN + n] = pr[192 + h * 32 + 16 + c];
  }
  if (tid < 48) {
    float r0 = pr[576 + tid], r1 = pr[576 + 48 + tid], r2 = pr[576 + 96 + tid];
    float x = R[0] * r0 + R[1] * r1 + R[2] * r2 + T[0];
    float y = R[3] * r0 + R[4] * r1 + R[5] * r2 + T[1];
    float z = R[6] * r0 + R[7] * r1 + R[8] * r2 + T[2];
    q_pts[(size_t)n * QPR + tid * 3 + 0] = x;
    q_pts[(size_t)n * QPR + tid * 3 + 1] = y;
    q_pts[(size_t)n * QPR + tid * 3 + 2] = z;
    sq_q[tid] = x * x + y * y + z * z;
  }
  if (tid >= 64 && tid < 208) {
    int t = tid - 64;
    float r0 = pr[720 + t], r1 = pr[720 + 144 + t], r2 = pr[720 + 288 + t];
    float x = R[0] * r0 + R[1] * r1 + R[2] * r2 + T[0];
    float y = R[3] * r0 + R[4] * r1 + R[5] * r2 + T[1];
    float z = R[6] * r0 + R[7] * r1 + R[8] * r2 + T[2];
    int h = t / 12, pp = t % 12;
    if (pp < 4) {
      int d = pp * 3;
      kpc[(size_t)(h * 12 + d + 0) * NN + n] = x;
      kpc[(size_t)(h * 12 + d + 1) * NN + n] = y;
      kpc[(size_t)(h * 12 + d + 2) * NN + n] = z;
      sq_k[h * 4 + pp] = x * x + y * y + z * z;
    } else {
      int d = (pp - 4) * 3;
      vpc[(size_t)(h * 24 + d + 0) * NN + n] = x;
      vpc[(size_t)(h * 24 + d + 1) * NN + n] = y;
      vpc[(size_t)(h * 24 + d + 2) * NN + n] = z;
    }
  }
  __syncthreads();
  if (tid < HH) {
    float a = 0.f, b = 0.f;
#pragma unroll
    for (int p = 0; p < 4; p++) { a += sq_q[tid * 4 + p]; b += sq_k[tid * 4 + p]; }
    qn[n * HH + tid] = a;
    knc[(size_t)tid * NN + n] = b;
  }
}

// ---------------------------------------------------------------------------
// bias_pass: B[i,h,j] = sum_c z[i,j,c]*wb[c,h] (bf16 out). wb transposed
// in-LDS from a coalesced linear read (no prep kernel).
// ---------------------------------------------------------------------------
__global__ __launch_bounds__(256) void bias_pass(
    const float* __restrict__ z, const float* __restrict__ wb,
    __hip_bfloat16* __restrict__ B)
{
  __shared__ float wb_s[HH * CZ];      // [h][c], 6 KB
  __shared__ float bias_s[HH * 128];   // 6 KB
  const int i = blockIdx.y;
  const int jb = blockIdx.x * 128;
  const int tid = threadIdx.x;
  const int jl = tid >> 2, csub = tid & 3;

  for (int e = tid; e < HH * CZ; e += 256) {
    int c = e / HH, h = e - c * HH;     // e = c*12+h, coalesced read
    wb_s[h * CZ + c] = wb[e];
  }
  __syncthreads();

  const float* zb = z + ((size_t)i * NN + jb + jl) * CZ + csub * 4;
  float4 zq0[8], zq1[8];
#pragma unroll
  for (int k8 = 0; k8 < 8; k8++)
    zq0[k8] = *reinterpret_cast<const float4*>(&zb[k8 * 16]);
#pragma unroll
  for (int k8 = 0; k8 < 8; k8++)
    zq1[k8] = *reinterpret_cast<const float4*>(&zb[(size_t)64 * CZ + k8 * 16]);

  float bd0[HH], bd1[HH];
#pragma unroll
  for (int h = 0; h < HH; h++) { bd0[h] = 0.f; bd1[h] = 0.f; }

#pragma unroll
  for (int k8 = 0; k8 < 8; k8++) {
    const int c = csub * 4 + k8 * 16;
#pragma unroll
    for (int h = 0; h < HH; h++) {
      float4 wv = *reinterpret_cast<const float4*>(&wb_s[h * CZ + c]);
      bd0[h] += dot4(zq0[k8], wv);
      bd1[h] += dot4(zq1[k8], wv);
    }
  }
#pragma unroll
  for (int h = 0; h < HH; h++) {
    bd0[h] += __shfl_xor(bd0[h], 1); bd0[h] += __shfl_xor(bd0[h], 2);
    bd1[h] += __shfl_xor(bd1[h], 1); bd1[h] += __shfl_xor(bd1[h], 2);
  }
  if (csub == 0) {
#pragma unroll
    for (int h = 0; h < HH; h++) {
      bias_s[h * 128 + jl] = bd0[h];
      bias_s[h * 128 + 64 + jl] = bd1[h];
    }
  }
  __syncthreads();
  for (int e = tid; e < HH * 128; e += 256) {
    int h = e >> 7, j2 = e & 127;
    B[((size_t)i * HH + h) * NN + jb + j2] = __float2bfloat16(bias_s[e]);
  }
}

// ---------------------------------------------------------------------------
// attn_logits: logits + row softmax -> normalized A (bf16), one WARP per
// (i,h). grid (NN/4, HH). Forced to 8 waves/EU (VGPR<=64, 32 waves/CU).
// ---------------------------------------------------------------------------
__global__ __launch_bounds__(256, 8) void attn_logits(
    const float* __restrict__ kc, const float* __restrict__ kpc,
    const float* __restrict__ knc, const float* __restrict__ proj,
    const float* __restrict__ q_pts, const float* __restrict__ qn,
    const float* __restrict__ bb, const float* __restrict__ head_w,
    const float* __restrict__ mask, __hip_bfloat16* __restrict__ A)
{
  const int h = blockIdx.y;
  const int i = blockIdx.x * 4 + (threadIdx.x >> 6);
  const int lane = threadIdx.x & 63;

  const float* qb = proj + (size_t)i * PROJW + h * 16;
  const float4 q0 = *reinterpret_cast<const float4*>(qb);
  const float4 q1 = *reinterpret_cast<const float4*>(qb + 4);
  const float4 q2 = *reinterpret_cast<const float4*>(qb + 8);
  const float4 q3 = *reinterpret_cast<const float4*>(qb + 12);
  const float* pb = q_pts + (size_t)i * QPR + h * 12;
  const float4 p0 = *reinterpret_cast<const float4*>(pb);
  const float4 p1 = *reinterpret_cast<const float4*>(pb + 4);
  const float4 p2 = *reinterpret_cast<const float4*>(pb + 8);
  const float qnv = qn[i * HH + h];
  const float bbv = bb[h];
  const float xw = head_w[h];
  const float hwv = ((xw > 20.f) ? xw : log1pf(__expf(xw))) * SC_PT;
  const float mi = mask[i];

  const float* kch  = kc  + (size_t)h * 16 * NN;
  const float* kpch = kpc + (size_t)h * 12 * NN;
  const float* knch = knc + (size_t)h * NN;
  __hip_bfloat16* Arow = A + ((size_t)i * HH + h) * NN;

  float4 av[4];
#pragma unroll
  for (int t = 0; t < 4; t++) {
    const int j = t * 256 + lane * 4;
    float4 d = {0, 0, 0, 0};
#pragma unroll
    for (int c = 0; c < 16; c++) {
      const float qc = (c < 4 ? (&q0.x)[c] : c < 8 ? (&q1.x)[c - 4]
                       : c < 12 ? (&q2.x)[c - 8] : (&q3.x)[c - 12]);
      float4 kv = *reinterpret_cast<const float4*>(&kch[(size_t)c * NN + j]);
      d.x += qc * kv.x; d.y += qc * kv.y; d.z += qc * kv.z; d.w += qc * kv.w;
    }
    float4 cr = {0, 0, 0, 0};
#pragma unroll
    for (int dd = 0; dd < 12; dd++) {
      const float pc = (dd < 4 ? (&p0.x)[dd] : dd < 8 ? (&p1.x)[dd - 4]
                        : (&p2.x)[dd - 8]);
      float4 kv = *reinterpret_cast<const float4*>(&kpch[(size_t)dd * NN + j]);
      cr.x += pc * kv.x; cr.y += pc * kv.y; cr.z += pc * kv.z; cr.w += pc * kv.w;
    }
    float4 kn4 = *reinterpret_cast<const float4*>(&knch[j]);
    ushort4 bu = *reinterpret_cast<const ushort4*>(&Arow[j]);
    float4 m4 = *reinterpret_cast<const float4*>(&mask[j]);
    av[t].x = SC_QK * d.x + SC_B * (bf2f(bu.x) + bbv)
              - 0.5f * hwv * (qnv + kn4.x - 2.f * cr.x) + INF_ * (mi * m4.x - 1.f);
    av[t].y = SC_QK * d.y + SC_B * (bf2f(bu.y) + bbv)
              - 0.5f * hwv * (qnv + kn4.y - 2.f * cr.y) + INF_ * (mi * m4.y - 1.f);
    av[t].z = SC_QK * d.z + SC_B * (bf2f(bu.z) + bbv)
              - 0.5f * hwv * (qnv + kn4.z - 2.f * cr.z) + INF_ * (mi * m4.z - 1.f);
    av[t].w = SC_QK * d.w + SC_B * (bf2f(bu.w) + bbv)
              - 0.5f * hwv * (qnv + kn4.w - 2.f * cr.w) + INF_ * (mi * m4.w - 1.f);
  }

  float m = av[0].x;
#pragma unroll
  for (int t = 0; t < 4; t++) {
    m = fmaxf(m, av[t].x); m = fmaxf(m, av[t].y);
    m = fmaxf(m, av[t].z); m = fmaxf(m, av[t].w);
  }
  for (int off = 32; off; off >>= 1) m = fmaxf(m, __shfl_xor(m, off));
  float ssum = 0.f;
#pragma unroll
  for (int t = 0; t < 4; t++) {
    av[t].x = __expf(av[t].x - m); ssum += av[t].x;
    av[t].y = __expf(av[t].y - m); ssum += av[t].y;
    av[t].z = __expf(av[t].z - m); ssum += av[t].z;
    av[t].w = __expf(av[t].w - m); ssum += av[t].w;
  }
  for (int off = 32; off; off >>= 1) ssum += __shfl_xor(ssum, off);
  const float inv = 1.f / ssum;
#pragma unroll
  for (int t = 0; t < 4; t++) {
    const int j = t * 256 + lane * 4;
    ushort4 st;
    st.x = f2bf(av[t].x * inv); st.y = f2bf(av[t].y * inv);
    st.z = f2bf(av[t].z * inv); st.w = f2bf(av[t].w * inv);
    *reinterpret_cast<ushort4*>(&Arow[j]) = st;
  }
}

// ---------------------------------------------------------------------------
// attn_out: o/o_pt = sum_j A[i,h,j] * {v,vp}. One WARP per (i,h).
// grid (NN/4, HH). Forced to 8 waves/EU (VGPR<=64, 32 waves/CU).
// ---------------------------------------------------------------------------
__global__ __launch_bounds__(256, 8) void attn_out(
    const float* __restrict__ vc, const float* __restrict__ vpc,
    const __hip_bfloat16* __restrict__ A,
    float* __restrict__ cat, float* __restrict__ optb)
{
  const int h = blockIdx.y;
  const int i = blockIdx.x * 4 + (threadIdx.x >> 6);
  const int lane = threadIdx.x & 63;

  const float* vch  = vc  + (size_t)h * 16 * NN;
  const float* vpch = vpc + (size_t)h * 24 * NN;
  const __hip_bfloat16* Arow = A + ((size_t)i * HH + h) * NN;

  float oacc[16], wacc[24];
#pragma unroll
  for (int c = 0; c < 16; c++) oacc[c] = 0.f;
#pragma unroll
  for (int d = 0; d < 24; d++) wacc[d] = 0.f;
#pragma unroll
  for (int t = 0; t < 4; t++) {
    const int j = t * 256 + lane * 4;
    ushort4 au = *reinterpret_cast<const ushort4*>(&Arow[j]);
    float4 a4 = make_float4(bf2f(au.x), bf2f(au.y), bf2f(au.z), bf2f(au.w));
#pragma unroll
    for (int c = 0; c < 16; c++) {
      float4 vv = *reinterpret_cast<const float4*>(&vch[(size_t)c * NN + j]);
      oacc[c] += dot4(a4, vv);
    }
#pragma unroll
    for (int d = 0; d < 24; d++) {
      float4 wv = *reinterpret_cast<const float4*>(&vpch[(size_t)d * NN + j]);
      wacc[d] += dot4(a4, wv);
    }
  }
  for (int off = 32; off; off >>= 1) {
#pragma unroll
    for (int c = 0; c < 16; c++) oacc[c] += __shfl_xor(oacc[c], off);
#pragma unroll
    for (int d = 0; d < 24; d++) wacc[d] += __shfl_xor(wacc[d], off);
  }
  if (lane == 0) {
    float* cr = cat + (size_t)i * DCAT + h * 16;
#pragma unroll
    for (int c = 0; c < 16; c++) cr[c] = oacc[c];
    float* ob = optb + ((size_t)i * HH + h) * 24;
#pragma unroll
    for (int d = 0; d < 24; d++) ob[d] = wacc[d];
  }
}

// ---------------------------------------------------------------------------
// opair_pass v4: split-j partial o_pair. grid (4, 1024).
// ---------------------------------------------------------------------------
__global__ __launch_bounds__(256) void opair_pass(
    const float* __restrict__ z, const __hip_bfloat16* __restrict__ A,
    float* __restrict__ partial)
{
  __shared__ float A_ls[256 * HH];  // 12 KB, [jloc][h]
  __shared__ float red[HH * CZ];    // 6 KB
  const int sp = blockIdx.x, i = blockIdx.y;
  const int jb = sp * 256;
  const int tid = threadIdx.x;
  const int c4 = (tid & 31) * 4, jsub = tid >> 5;

  for (int e = tid; e < HH * 64; e += 256) {
    int h = e >> 6, j4 = (e & 63) * 4;
    ushort4 au = *reinterpret_cast<const ushort4*>(
        &A[((size_t)i * HH + h) * NN + jb + j4]);
    A_ls[(j4 + 0) * HH + h] = bf2f(au.x);
    A_ls[(j4 + 1) * HH + h] = bf2f(au.y);
    A_ls[(j4 + 2) * HH + h] = bf2f(au.z);
    A_ls[(j4 + 3) * HH + h] = bf2f(au.w);
  }
  for (int e = tid; e < HH * CZ; e += 256) red[e] = 0.f;
  __syncthreads();

  float4 acc[HH];
#pragma unroll
  for (int h = 0; h < HH; h++) acc[h] = make_float4(0.f, 0.f, 0.f, 0.f);

  const float* zrow = z + ((size_t)i * NN + jb + jsub * 32) * CZ + c4;
  const float* arow = &A_ls[jsub * 32 * HH];
  for (int j0 = 0; j0 < 32; j0 += 4) {
#pragma unroll
    for (int jj = 0; jj < 4; jj++) {
      const int j = j0 + jj;
      float4 zq = *reinterpret_cast<const float4*>(&zrow[(size_t)j * CZ]);
      float4 a0 = *reinterpret_cast<const float4*>(&arow[j * HH]);
      float4 a1 = *reinterpret_cast<const float4*>(&arow[j * HH + 4]);
      float4 a2 = *reinterpret_cast<const float4*>(&arow[j * HH + 8]);
      acc[0].x += a0.x * zq.x; acc[0].y += a0.x * zq.y;
      acc[0].z += a0.x * zq.z; acc[0].w += a0.x * zq.w;
      acc[1].x += a0.y * zq.x; acc[1].y += a0.y * zq.y;
      acc[1].z += a0.y * zq.z; acc[1].w += a0.y * zq.w;
      acc[2].x += a0.z * zq.x; acc[2].y += a0.z * zq.y;
      acc[2].z += a0.z * zq.z; acc[2].w += a0.z * zq.w;
      acc[3].x += a0.w * zq.x; acc[3].y += a0.w * zq.y;
      acc[3].z += a0.w * zq.z; acc[3].w += a0.w * zq.w;
      acc[4].x += a1.x * zq.x; acc[4].y += a1.x * zq.y;
      acc[4].z += a1.x * zq.z; acc[4].w += a1.x * zq.w;
      acc[5].x += a1.y * zq.x; acc[5].y += a1.y * zq.y;
      acc[5].z += a1.y * zq.z; acc[5].w += a1.y * zq.w;
      acc[6].x += a1.z * zq.x; acc[6].y += a1.z * zq.y;
      acc[6].z += a1.z * zq.z; acc[6].w += a1.z * zq.w;
      acc[7].x += a1.w * zq.x; acc[7].y += a1.w * zq.y;
      acc[7].z += a1.w * zq.z; acc[7].w += a1.w * zq.w;
      acc[8].x += a2.x * zq.x; acc[8].y += a2.x * zq.y;
      acc[8].z += a2.x * zq.z; acc[8].w += a2.x * zq.w;
      acc[9].x += a2.y * zq.x; acc[9].y += a2.y * zq.y;
      acc[9].z += a2.y * zq.z; acc[9].w += a2.y * zq.w;
      acc[10].x += a2.z * zq.x; acc[10].y += a2.z * zq.y;
      acc[10].z += a2.z * zq.z; acc[10].w += a2.z * zq.w;
      acc[11].x += a2.w * zq.x; acc[11].y += a2.w * zq.y;
      acc[11].z += a2.w * zq.z; acc[11].w += a2.w * zq.w;
    }
  }
  for (int s = 0; s < 8; s++) {
    __syncthreads();
    if (jsub == s) {
#pragma unroll
      for (int h = 0; h < HH; h++) {
        red[h * CZ + c4 + 0] += acc[h].x;
        red[h * CZ + c4 + 1] += acc[h].y;
        red[h * CZ + c4 + 2] += acc[h].z;
        red[h * CZ + c4 + 3] += acc[h].w;
      }
    }
  }
  __syncthreads();
  float* pp = partial + ((size_t)(i * 4 + sp)) * (HH * CZ);
  for (int e = tid; e < HH * CZ; e += 256) pp[e] = red[e];
}

// ---------------------------------------------------------------------------
// opair_reduce (+fused finish): sum 4 partials -> cat[576:2112];
// inverse-rotate o_pt + norms -> cat[192:576]. grid NN, block 256.
// ---------------------------------------------------------------------------
__global__ __launch_bounds__(256) void opair_reduce(
    const float* __restrict__ partial, const float* __restrict__ optb,
    const float* __restrict__ rot, const float* __restrict__ trans,
    float* __restrict__ cat)
{
  const int i = blockIdx.x, tid = threadIdx.x;
  __shared__ float R_s[9], T_s[3];
  if (tid < 9) R_s[tid] = rot[i * 9 + tid];
  if (tid < 3) T_s[tid] = trans[i * 3 + tid];
  __syncthreads();

  const float* pp = partial + ((size_t)i * 4) * (HH * CZ);
  for (int e = tid; e < HH * CZ; e += 256) {
    float v = pp[e] + pp[HH * CZ + e] + pp[2 * HH * CZ + e] + pp[3 * HH * CZ + e];
    cat[(size_t)i * DCAT + 576 + e] = v;
  }
  if (tid < 96) {
    int h = tid >> 3, p = tid & 7;
    const float* ob = optb + ((size_t)i * HH + h) * 24 + p * 3;
    float gx = ob[0] - T_s[0];
    float gy = ob[1] - T_s[1];
    float gz = ob[2] - T_s[2];
    float lx = R_s[0] * gx + R_s[3] * gy + R_s[6] * gz;
    float ly = R_s[1] * gx + R_s[4] * gy + R_s[7] * gz;
    float lz = R_s[2] * gx + R_s[5] * gy + R_s[8] * gz;
    float* catr = cat + (size_t)i * DCAT;
    catr[192 + 0 * 96 + h * 8 + p] = lx;
    catr[192 + 1 * 96 + h * 8 + p] = ly;
    catr[192 + 2 * 96 + h * 8 + p] = lz;
    catr[480 + h * 8 + p] = sqrtf(lx * lx + ly * ly + lz * lz + 1e-8f);
  }
}

// ---------------------------------------------------------------------------
// out_gemm: out = cat @ wout + bout  (1024 x 2112 x 384)
// ---------------------------------------------------------------------------
__global__ __launch_bounds__(256) void out_gemm(
    const float* __restrict__ cat, const float* __restrict__ wout,
    const float* __restrict__ bout, float* __restrict__ out)
{
  __shared__ float c_lds[4 * DCAT];
  const int n0 = blockIdx.x * 4;
  const int cq = blockIdx.y * 128 + (threadIdx.x & 63) * 2;
  const int rg = threadIdx.x >> 6;
  for (int idx = threadIdx.x; idx < 4 * DCAT; idx += 256) {
    int r = idx / DCAT, kk = idx - r * DCAT;
    c_lds[idx] = cat[(size_t)(n0 + r) * DCAT + kk];
  }
  __syncthreads();
  float a0 = 0.f, a1 = 0.f;
  const float* crow = &c_lds[rg * DCAT];
#pragma unroll 4
  for (int kk = 0; kk < DCAT; kk++) {
    float cv = crow[kk];
    float2 w2 = *reinterpret_cast<const float2*>(&wout[(size_t)kk * CS + cq]);
    a0 += cv * w2.x; a1 += cv * w2.y;
  }
  float* o = out + (size_t)(n0 + rg) * CS + cq;
  o[0] = a0 + bout[cq]; o[1] = a1 + bout[cq + 1];
}

// ---------------------------------------------------------------------------
extern "C" void kernel_launch(void* const* d_in, const int* in_sizes, int n_in,
                              void* d_out, int out_size, void* d_ws, size_t ws_size,
                              hipStream_t stream) {
  const float* s      = (const float*)d_in[0];
  const float* z      = (const float*)d_in[1];
  const float* rot    = (const float*)d_in[2];
  const float* trans  = (const float*)d_in[3];
  const float* mask   = (const float*)d_in[4];
  const float* wq     = (const float*)d_in[5];
  const float* bq     = (const float*)d_in[6];
  const float* wkv    = (const float*)d_in[7];
  const float* bkv    = (const float*)d_in[8];
  const float* wqp    = (const float*)d_in[9];
  const float* bqp    = (const float*)d_in[10];
  const float* wkvp   = (const float*)d_in[11];
  const float* bkvp   = (const float*)d_in[12];
  const float* wb     = (const float*)d_in[13];
  const float* bb     = (const float*)d_in[14];
  const float* head_w = (const float*)d_in[15];
  const float* wout   = (const float*)d_in[16];
  const float* bout   = (const float*)d_in[17];
  float* out = (float*)d_out;

  // workspace layout (floats; all bases 16-float aligned)
  float* ws = (float*)d_ws;
  float* proj_buf = ws;                                  // 1,179,648
  float* kc_buf   = proj_buf + (size_t)NN * PROJW;       // 196,608
  float* vc_buf   = kc_buf + (size_t)HH * 16 * NN;       // 196,608
  float* kpc_buf  = vc_buf + (size_t)HH * 16 * NN;       // 147,456
  float* vpc_buf  = kpc_buf + (size_t)HH * 12 * NN;      // 294,912
  float* knc_buf  = vpc_buf + (size_t)HH * 24 * NN;      // 12,288
  float* qpts_buf = knc_buf + (size_t)HH * NN;           // 147,456
  float* qn_buf   = qpts_buf + (size_t)NN * QPR;         // 12,288
  float* optb_buf = qn_buf + NN * HH + 16;               // 294,912
  float* cat_buf  = optb_buf + (size_t)NN * HH * 24;     // 2,162,688
  float* part_buf = cat_buf + (size_t)NN * DCAT;         // 6,291,456
  __hip_bfloat16* A_buf =
      (__hip_bfloat16*)(part_buf + (size_t)4 * NN * HH * CZ);  // 12,582,912 bf16

  proj_all<<<dim3(NN / 8, 9), dim3(256), 0, stream>>>(
      s, wq, bq, wkv, bkv, wqp, bqp, wkvp, bkvp, proj_buf);
  ipa_transform<<<dim3(NN), dim3(256), 0, stream>>>(
      proj_buf, rot, trans, kc_buf, vc_buf, qpts_buf, kpc_buf, vpc_buf,
      qn_buf, knc_buf);
  bias_pass<<<dim3(8, NN), dim3(256), 0, stream>>>(z, wb, A_buf);
  attn_logits<<<dim3(NN / 4, HH), dim3(256), 0, stream>>>(
      kc_buf, kpc_buf, knc_buf, proj_buf, qpts_buf, qn_buf,
      bb, head_w, mask, A_buf);
  attn_out<<<dim3(NN / 4, HH), dim3(256), 0, stream>>>(
      vc_buf, vpc_buf, A_buf, cat_buf, optb_buf);
  opair_pass<<<dim3(4, NN), dim3(256), 0, stream>>>(z, A_buf, part_buf);
  opair_reduce<<<dim3(NN), dim3(256), 0, stream>>>(
      part_buf, optb_buf, rot, trans, cat_buf);
  out_gemm<<<dim3(NN / 4, 3), dim3(256), 0, stream>>>(
      cat_buf, wout, bout, out);
}

// Round 15
// 671.607 us; speedup vs baseline: 1.6256x; 1.6256x over previous
//
#include <hip/hip_runtime.h>
#include <hip/hip_bf16.h>
#include <math.h>

// Problem constants
#define NN   1024
#define CS   384
#define CZ   128
#define HH   12
#define HCH  192
#define QPR  144
#define DCAT 2112
#define PROJW 1152    // 192+384+144+432
#define INF_ 100000.0f

#define SC_QK 0.14433756729740643f   // sqrt(1/48)
#define SC_B  0.5773502691896258f    // sqrt(1/3)
#define SC_PT 0.13608276348795434f   // sqrt(1/54)

__device__ __forceinline__ float dot4(float4 a, float4 b) {
  return a.x * b.x + a.y * b.y + a.z * b.z + a.w * b.w;
}
__device__ __forceinline__ float bf2f(unsigned short u) {
  unsigned int v = ((unsigned int)u) << 16;
  float f; __builtin_memcpy(&f, &v, 4); return f;
}
__device__ __forceinline__ unsigned short f2bf(float f) {
  __hip_bfloat16 h = __float2bfloat16(f);
  unsigned short u; __builtin_memcpy(&u, &h, 2); return u;
}

// ---------------------------------------------------------------------------
// proj_all: fused s @ {wq,wkv,wqp,wkvp} + bias -> proj[n][1152]
// ---------------------------------------------------------------------------
__global__ __launch_bounds__(256) void proj_all(
    const float* __restrict__ s,
    const float* __restrict__ wq, const float* __restrict__ bq,
    const float* __restrict__ wkv, const float* __restrict__ bkv,
    const float* __restrict__ wqp, const float* __restrict__ bqp,
    const float* __restrict__ wkvp, const float* __restrict__ bkvp,
    float* __restrict__ proj)
{
  __shared__ float s_lds[8 * CS];
  const int n0 = blockIdx.x * 8;
  for (int idx = threadIdx.x; idx < 8 * CS; idx += 256)
    s_lds[idx] = s[(size_t)(n0 + idx / CS) * CS + (idx % CS)];
  __syncthreads();

  const int gc = blockIdx.y * 128 + (threadIdx.x & 31) * 4;
  const int rg = threadIdx.x >> 5;
  const float* wp; const float* bp; int OUT, lc;
  if (gc < 192)      { wp = wq;   bp = bq;   OUT = 192; lc = gc; }
  else if (gc < 576) { wp = wkv;  bp = bkv;  OUT = 384; lc = gc - 192; }
  else if (gc < 720) { wp = wqp;  bp = bqp;  OUT = 144; lc = gc - 576; }
  else               { wp = wkvp; bp = bkvp; OUT = 432; lc = gc - 720; }

  float a0 = 0.f, a1 = 0.f, a2 = 0.f, a3 = 0.f;
  const float* srow = &s_lds[rg * CS];
#pragma unroll 4
  for (int kk = 0; kk < CS; kk++) {
    float sv = srow[kk];
    float4 w4 = *reinterpret_cast<const float4*>(&wp[(size_t)kk * OUT + lc]);
    a0 += sv * w4.x; a1 += sv * w4.y; a2 += sv * w4.z; a3 += sv * w4.w;
  }
  float* o = proj + (size_t)(n0 + rg) * PROJW + gc;
  o[0] = a0 + bp[lc]; o[1] = a1 + bp[lc + 1];
  o[2] = a2 + bp[lc + 2]; o[3] = a3 + bp[lc + 3];
}

// ---------------------------------------------------------------------------
// transform: split kv, rotate/translate points, write COMPONENT-MAJOR layouts
// ---------------------------------------------------------------------------
__global__ __launch_bounds__(256) void ipa_transform(
    const float* __restrict__ proj, const float* __restrict__ rot,
    const float* __restrict__ trans,
    float* __restrict__ kc, float* __restrict__ vc,
    float* __restrict__ q_pts, float* __restrict__ kpc,
    float* __restrict__ vpc, float* __restrict__ qn, float* __restrict__ knc)
{
  const int n = blockIdx.x, tid = threadIdx.x;
  const float* pr = proj + (size_t)n * PROJW;
  __shared__ float R[9], T[3], sq_q[48], sq_k[48];
  if (tid < 9) R[tid] = rot[n * 9 + tid];
  if (tid < 3) T[tid] = trans[n * 3 + tid];
  __syncthreads();
  if (tid < HCH) {
    int h = tid >> 4, c = tid & 15;
    kc[(size_t)(h * 16 + c) * NN + n] = pr[192 + h * 32 + c];
    vc[(size_t)(h * 16 + c) * NN + n] = pr[192 + h * 32 + 16 + c];
  }
  if (tid < 48) {
    float r0 = pr[576 + tid], r1 = pr[576 + 48 + tid], r2 = pr[576 + 96 + tid];
    float x = R[0] * r0 + R[1] * r1 + R[2] * r2 + T[0];
    float y = R[3] * r0 + R[4] * r1 + R[5] * r2 + T[1];
    float z = R[6] * r0 + R[7] * r1 + R[8] * r2 + T[2];
    q_pts[(size_t)n * QPR + tid * 3 + 0] = x;
    q_pts[(size_t)n * QPR + tid * 3 + 1] = y;
    q_pts[(size_t)n * QPR + tid * 3 + 2] = z;
    sq_q[tid] = x * x + y * y + z * z;
  }
  if (tid >= 64 && tid < 208) {
    int t = tid - 64;
    float r0 = pr[720 + t], r1 = pr[720 + 144 + t], r2 = pr[720 + 288 + t];
    float x = R[0] * r0 + R[1] * r1 + R[2] * r2 + T[0];
    float y = R[3] * r0 + R[4] * r1 + R[5] * r2 + T[1];
    float z = R[6] * r0 + R[7] * r1 + R[8] * r2 + T[2];
    int h = t / 12, pp = t % 12;
    if (pp < 4) {
      int d = pp * 3;
      kpc[(size_t)(h * 12 + d + 0) * NN + n] = x;
      kpc[(size_t)(h * 12 + d + 1) * NN + n] = y;
      kpc[(size_t)(h * 12 + d + 2) * NN + n] = z;
      sq_k[h * 4 + pp] = x * x + y * y + z * z;
    } else {
      int d = (pp - 4) * 3;
      vpc[(size_t)(h * 24 + d + 0) * NN + n] = x;
      vpc[(size_t)(h * 24 + d + 1) * NN + n] = y;
      vpc[(size_t)(h * 24 + d + 2) * NN + n] = z;
    }
  }
  __syncthreads();
  if (tid < HH) {
    float a = 0.f, b = 0.f;
#pragma unroll
    for (int p = 0; p < 4; p++) { a += sq_q[tid * 4 + p]; b += sq_k[tid * 4 + p]; }
    qn[n * HH + tid] = a;
    knc[(size_t)tid * NN + n] = b;
  }
}

// ---------------------------------------------------------------------------
// bias_pass: B[i,h,j] = sum_c z[i,j,c]*wb[c,h] (bf16 out). wb transposed
// in-LDS from a coalesced linear read (no prep kernel).
// ---------------------------------------------------------------------------
__global__ __launch_bounds__(256) void bias_pass(
    const float* __restrict__ z, const float* __restrict__ wb,
    __hip_bfloat16* __restrict__ B)
{
  __shared__ float wb_s[HH * CZ];      // [h][c], 6 KB
  __shared__ float bias_s[HH * 128];   // 6 KB
  const int i = blockIdx.y;
  const int jb = blockIdx.x * 128;
  const int tid = threadIdx.x;
  const int jl = tid >> 2, csub = tid & 3;

  for (int e = tid; e < HH * CZ; e += 256) {
    int c = e / HH, h = e - c * HH;     // e = c*12+h, coalesced read
    wb_s[h * CZ + c] = wb[e];
  }
  __syncthreads();

  const float* zb = z + ((size_t)i * NN + jb + jl) * CZ + csub * 4;
  float4 zq0[8], zq1[8];
#pragma unroll
  for (int k8 = 0; k8 < 8; k8++)
    zq0[k8] = *reinterpret_cast<const float4*>(&zb[k8 * 16]);
#pragma unroll
  for (int k8 = 0; k8 < 8; k8++)
    zq1[k8] = *reinterpret_cast<const float4*>(&zb[(size_t)64 * CZ + k8 * 16]);

  float bd0[HH], bd1[HH];
#pragma unroll
  for (int h = 0; h < HH; h++) { bd0[h] = 0.f; bd1[h] = 0.f; }

#pragma unroll
  for (int k8 = 0; k8 < 8; k8++) {
    const int c = csub * 4 + k8 * 16;
#pragma unroll
    for (int h = 0; h < HH; h++) {
      float4 wv = *reinterpret_cast<const float4*>(&wb_s[h * CZ + c]);
      bd0[h] += dot4(zq0[k8], wv);
      bd1[h] += dot4(zq1[k8], wv);
    }
  }
#pragma unroll
  for (int h = 0; h < HH; h++) {
    bd0[h] += __shfl_xor(bd0[h], 1); bd0[h] += __shfl_xor(bd0[h], 2);
    bd1[h] += __shfl_xor(bd1[h], 1); bd1[h] += __shfl_xor(bd1[h], 2);
  }
  if (csub == 0) {
#pragma unroll
    for (int h = 0; h < HH; h++) {
      bias_s[h * 128 + jl] = bd0[h];
      bias_s[h * 128 + 64 + jl] = bd1[h];
    }
  }
  __syncthreads();
  for (int e = tid; e < HH * 128; e += 256) {
    int h = e >> 7, j2 = e & 127;
    B[((size_t)i * HH + h) * NN + jb + j2] = __float2bfloat16(bias_s[e]);
  }
}

// ---------------------------------------------------------------------------
// attn_logits: logits + row softmax -> normalized A (bf16), one WARP per
// (i,h). grid (NN/4, HH). Natural register allocation (no min-wave forcing).
// ---------------------------------------------------------------------------
__global__ __launch_bounds__(256) void attn_logits(
    const float* __restrict__ kc, const float* __restrict__ kpc,
    const float* __restrict__ knc, const float* __restrict__ proj,
    const float* __restrict__ q_pts, const float* __restrict__ qn,
    const float* __restrict__ bb, const float* __restrict__ head_w,
    const float* __restrict__ mask, __hip_bfloat16* __restrict__ A)
{
  const int h = blockIdx.y;
  const int i = blockIdx.x * 4 + (threadIdx.x >> 6);
  const int lane = threadIdx.x & 63;

  const float* qb = proj + (size_t)i * PROJW + h * 16;
  const float4 q0 = *reinterpret_cast<const float4*>(qb);
  const float4 q1 = *reinterpret_cast<const float4*>(qb + 4);
  const float4 q2 = *reinterpret_cast<const float4*>(qb + 8);
  const float4 q3 = *reinterpret_cast<const float4*>(qb + 12);
  const float* pb = q_pts + (size_t)i * QPR + h * 12;
  const float4 p0 = *reinterpret_cast<const float4*>(pb);
  const float4 p1 = *reinterpret_cast<const float4*>(pb + 4);
  const float4 p2 = *reinterpret_cast<const float4*>(pb + 8);
  const float qnv = qn[i * HH + h];
  const float bbv = bb[h];
  const float xw = head_w[h];
  const float hwv = ((xw > 20.f) ? xw : log1pf(__expf(xw))) * SC_PT;
  const float mi = mask[i];

  const float* kch  = kc  + (size_t)h * 16 * NN;
  const float* kpch = kpc + (size_t)h * 12 * NN;
  const float* knch = knc + (size_t)h * NN;
  __hip_bfloat16* Arow = A + ((size_t)i * HH + h) * NN;

  float4 av[4];
#pragma unroll
  for (int t = 0; t < 4; t++) {
    const int j = t * 256 + lane * 4;
    float4 d = {0, 0, 0, 0};
#pragma unroll
    for (int c = 0; c < 16; c++) {
      const float qc = (c < 4 ? (&q0.x)[c] : c < 8 ? (&q1.x)[c - 4]
                       : c < 12 ? (&q2.x)[c - 8] : (&q3.x)[c - 12]);
      float4 kv = *reinterpret_cast<const float4*>(&kch[(size_t)c * NN + j]);
      d.x += qc * kv.x; d.y += qc * kv.y; d.z += qc * kv.z; d.w += qc * kv.w;
    }
    float4 cr = {0, 0, 0, 0};
#pragma unroll
    for (int dd = 0; dd < 12; dd++) {
      const float pc = (dd < 4 ? (&p0.x)[dd] : dd < 8 ? (&p1.x)[dd - 4]
                        : (&p2.x)[dd - 8]);
      float4 kv = *reinterpret_cast<const float4*>(&kpch[(size_t)dd * NN + j]);
      cr.x += pc * kv.x; cr.y += pc * kv.y; cr.z += pc * kv.z; cr.w += pc * kv.w;
    }
    float4 kn4 = *reinterpret_cast<const float4*>(&knch[j]);
    ushort4 bu = *reinterpret_cast<const ushort4*>(&Arow[j]);
    float4 m4 = *reinterpret_cast<const float4*>(&mask[j]);
    av[t].x = SC_QK * d.x + SC_B * (bf2f(bu.x) + bbv)
              - 0.5f * hwv * (qnv + kn4.x - 2.f * cr.x) + INF_ * (mi * m4.x - 1.f);
    av[t].y = SC_QK * d.y + SC_B * (bf2f(bu.y) + bbv)
              - 0.5f * hwv * (qnv + kn4.y - 2.f * cr.y) + INF_ * (mi * m4.y - 1.f);
    av[t].z = SC_QK * d.z + SC_B * (bf2f(bu.z) + bbv)
              - 0.5f * hwv * (qnv + kn4.z - 2.f * cr.z) + INF_ * (mi * m4.z - 1.f);
    av[t].w = SC_QK * d.w + SC_B * (bf2f(bu.w) + bbv)
              - 0.5f * hwv * (qnv + kn4.w - 2.f * cr.w) + INF_ * (mi * m4.w - 1.f);
  }

  float m = av[0].x;
#pragma unroll
  for (int t = 0; t < 4; t++) {
    m = fmaxf(m, av[t].x); m = fmaxf(m, av[t].y);
    m = fmaxf(m, av[t].z); m = fmaxf(m, av[t].w);
  }
  for (int off = 32; off; off >>= 1) m = fmaxf(m, __shfl_xor(m, off));
  float ssum = 0.f;
#pragma unroll
  for (int t = 0; t < 4; t++) {
    av[t].x = __expf(av[t].x - m); ssum += av[t].x;
    av[t].y = __expf(av[t].y - m); ssum += av[t].y;
    av[t].z = __expf(av[t].z - m); ssum += av[t].z;
    av[t].w = __expf(av[t].w - m); ssum += av[t].w;
  }
  for (int off = 32; off; off >>= 1) ssum += __shfl_xor(ssum, off);
  const float inv = 1.f / ssum;
#pragma unroll
  for (int t = 0; t < 4; t++) {
    const int j = t * 256 + lane * 4;
    ushort4 st;
    st.x = f2bf(av[t].x * inv); st.y = f2bf(av[t].y * inv);
    st.z = f2bf(av[t].z * inv); st.w = f2bf(av[t].w * inv);
    *reinterpret_cast<ushort4*>(&Arow[j]) = st;
  }
}

// ---------------------------------------------------------------------------
// attn_out v2: task-grouped + i-batched. Warp = (task t, 4 consecutive i).
// t in [0,60): h = t/5, grp = t%5 -> 8 output components (v rows or vp rows).
// Lane spans j; per j-step: 8 shared row loads + 4 A loads + 32 FMAs.
// 32 accumulators/thread, ~70 VGPR, no forcing, no spill.
// grid (NN/4, 15), block 256 (4 warps = 4 tasks).
// ---------------------------------------------------------------------------
__global__ __launch_bounds__(256) void attn_out(
    const float* __restrict__ vc, const float* __restrict__ vpc,
    const __hip_bfloat16* __restrict__ A,
    float* __restrict__ cat, float* __restrict__ optb)
{
  const int w = threadIdx.x >> 6, lane = threadIdx.x & 63;
  const int t = blockIdx.y * 4 + w;
  const int h = t / 5, grp = t - h * 5;
  const int i0 = blockIdx.x * 4;

  const float* base = (grp < 2)
      ? vc + (size_t)(h * 16 + grp * 8) * NN
      : vpc + (size_t)(h * 24 + (grp - 2) * 8) * NN;
  const unsigned short* A0 = reinterpret_cast<const unsigned short*>(A)
                             + ((size_t)i0 * HH + h) * NN;
  const unsigned short* A1 = A0 + (size_t)HH * NN;
  const unsigned short* A2 = A1 + (size_t)HH * NN;
  const unsigned short* A3 = A2 + (size_t)HH * NN;

  float acc0[8], acc1[8], acc2[8], acc3[8];
#pragma unroll
  for (int r = 0; r < 8; r++) { acc0[r] = 0.f; acc1[r] = 0.f; acc2[r] = 0.f; acc3[r] = 0.f; }

#pragma unroll 2
  for (int it = 0; it < 16; it++) {
    const int j = it * 64 + lane;
    float vv[8];
#pragma unroll
    for (int r = 0; r < 8; r++) vv[r] = base[(size_t)r * NN + j];
    const float a0 = bf2f(A0[j]);
    const float a1 = bf2f(A1[j]);
    const float a2 = bf2f(A2[j]);
    const float a3 = bf2f(A3[j]);
#pragma unroll
    for (int r = 0; r < 8; r++) {
      acc0[r] += a0 * vv[r];
      acc1[r] += a1 * vv[r];
      acc2[r] += a2 * vv[r];
      acc3[r] += a3 * vv[r];
    }
  }
  for (int off = 32; off; off >>= 1) {
#pragma unroll
    for (int r = 0; r < 8; r++) {
      acc0[r] += __shfl_xor(acc0[r], off);
      acc1[r] += __shfl_xor(acc1[r], off);
      acc2[r] += __shfl_xor(acc2[r], off);
      acc3[r] += __shfl_xor(acc3[r], off);
    }
  }
  if (lane == 0) {
    if (grp < 2) {
      const int co = h * 16 + grp * 8;
      float* c0 = cat + (size_t)(i0 + 0) * DCAT + co;
      float* c1 = cat + (size_t)(i0 + 1) * DCAT + co;
      float* c2 = cat + (size_t)(i0 + 2) * DCAT + co;
      float* c3 = cat + (size_t)(i0 + 3) * DCAT + co;
#pragma unroll
      for (int r = 0; r < 8; r++) {
        c0[r] = acc0[r]; c1[r] = acc1[r]; c2[r] = acc2[r]; c3[r] = acc3[r];
      }
    } else {
      const int doff = (grp - 2) * 8;
      float* o0 = optb + ((size_t)(i0 + 0) * HH + h) * 24 + doff;
      float* o1 = optb + ((size_t)(i0 + 1) * HH + h) * 24 + doff;
      float* o2 = optb + ((size_t)(i0 + 2) * HH + h) * 24 + doff;
      float* o3 = optb + ((size_t)(i0 + 3) * HH + h) * 24 + doff;
#pragma unroll
      for (int r = 0; r < 8; r++) {
        o0[r] = acc0[r]; o1[r] = acc1[r]; o2[r] = acc2[r]; o3[r] = acc3[r];
      }
    }
  }
}

// ---------------------------------------------------------------------------
// opair_pass v4: split-j partial o_pair. grid (4, 1024).
// ---------------------------------------------------------------------------
__global__ __launch_bounds__(256) void opair_pass(
    const float* __restrict__ z, const __hip_bfloat16* __restrict__ A,
    float* __restrict__ partial)
{
  __shared__ float A_ls[256 * HH];  // 12 KB, [jloc][h]
  __shared__ float red[HH * CZ];    // 6 KB
  const int sp = blockIdx.x, i = blockIdx.y;
  const int jb = sp * 256;
  const int tid = threadIdx.x;
  const int c4 = (tid & 31) * 4, jsub = tid >> 5;

  for (int e = tid; e < HH * 64; e += 256) {
    int h = e >> 6, j4 = (e & 63) * 4;
    ushort4 au = *reinterpret_cast<const ushort4*>(
        &A[((size_t)i * HH + h) * NN + jb + j4]);
    A_ls[(j4 + 0) * HH + h] = bf2f(au.x);
    A_ls[(j4 + 1) * HH + h] = bf2f(au.y);
    A_ls[(j4 + 2) * HH + h] = bf2f(au.z);
    A_ls[(j4 + 3) * HH + h] = bf2f(au.w);
  }
  for (int e = tid; e < HH * CZ; e += 256) red[e] = 0.f;
  __syncthreads();

  float4 acc[HH];
#pragma unroll
  for (int h = 0; h < HH; h++) acc[h] = make_float4(0.f, 0.f, 0.f, 0.f);

  const float* zrow = z + ((size_t)i * NN + jb + jsub * 32) * CZ + c4;
  const float* arow = &A_ls[jsub * 32 * HH];
  for (int j0 = 0; j0 < 32; j0 += 4) {
#pragma unroll
    for (int jj = 0; jj < 4; jj++) {
      const int j = j0 + jj;
      float4 zq = *reinterpret_cast<const float4*>(&zrow[(size_t)j * CZ]);
      float4 a0 = *reinterpret_cast<const float4*>(&arow[j * HH]);
      float4 a1 = *reinterpret_cast<const float4*>(&arow[j * HH + 4]);
      float4 a2 = *reinterpret_cast<const float4*>(&arow[j * HH + 8]);
      acc[0].x += a0.x * zq.x; acc[0].y += a0.x * zq.y;
      acc[0].z += a0.x * zq.z; acc[0].w += a0.x * zq.w;
      acc[1].x += a0.y * zq.x; acc[1].y += a0.y * zq.y;
      acc[1].z += a0.y * zq.z; acc[1].w += a0.y * zq.w;
      acc[2].x += a0.z * zq.x; acc[2].y += a0.z * zq.y;
      acc[2].z += a0.z * zq.z; acc[2].w += a0.z * zq.w;
      acc[3].x += a0.w * zq.x; acc[3].y += a0.w * zq.y;
      acc[3].z += a0.w * zq.z; acc[3].w += a0.w * zq.w;
      acc[4].x += a1.x * zq.x; acc[4].y += a1.x * zq.y;
      acc[4].z += a1.x * zq.z; acc[4].w += a1.x * zq.w;
      acc[5].x += a1.y * zq.x; acc[5].y += a1.y * zq.y;
      acc[5].z += a1.y * zq.z; acc[5].w += a1.y * zq.w;
      acc[6].x += a1.z * zq.x; acc[6].y += a1.z * zq.y;
      acc[6].z += a1.z * zq.z; acc[6].w += a1.z * zq.w;
      acc[7].x += a1.w * zq.x; acc[7].y += a1.w * zq.y;
      acc[7].z += a1.w * zq.z; acc[7].w += a1.w * zq.w;
      acc[8].x += a2.x * zq.x; acc[8].y += a2.x * zq.y;
      acc[8].z += a2.x * zq.z; acc[8].w += a2.x * zq.w;
      acc[9].x += a2.y * zq.x; acc[9].y += a2.y * zq.y;
      acc[9].z += a2.y * zq.z; acc[9].w += a2.y * zq.w;
      acc[10].x += a2.z * zq.x; acc[10].y += a2.z * zq.y;
      acc[10].z += a2.z * zq.z; acc[10].w += a2.z * zq.w;
      acc[11].x += a2.w * zq.x; acc[11].y += a2.w * zq.y;
      acc[11].z += a2.w * zq.z; acc[11].w += a2.w * zq.w;
    }
  }
  for (int s = 0; s < 8; s++) {
    __syncthreads();
    if (jsub == s) {
#pragma unroll
      for (int h = 0; h < HH; h++) {
        red[h * CZ + c4 + 0] += acc[h].x;
        red[h * CZ + c4 + 1] += acc[h].y;
        red[h * CZ + c4 + 2] += acc[h].z;
        red[h * CZ + c4 + 3] += acc[h].w;
      }
    }
  }
  __syncthreads();
  float* pp = partial + ((size_t)(i * 4 + sp)) * (HH * CZ);
  for (int e = tid; e < HH * CZ; e += 256) pp[e] = red[e];
}

// ---------------------------------------------------------------------------
// opair_reduce (+fused finish): sum 4 partials -> cat[576:2112];
// inverse-rotate o_pt + norms -> cat[192:576]. grid NN, block 256.
// ---------------------------------------------------------------------------
__global__ __launch_bounds__(256) void opair_reduce(
    const float* __restrict__ partial, const float* __restrict__ optb,
    const float* __restrict__ rot, const float* __restrict__ trans,
    float* __restrict__ cat)
{
  const int i = blockIdx.x, tid = threadIdx.x;
  __shared__ float R_s[9], T_s[3];
  if (tid < 9) R_s[tid] = rot[i * 9 + tid];
  if (tid < 3) T_s[tid] = trans[i * 3 + tid];
  __syncthreads();

  const float* pp = partial + ((size_t)i * 4) * (HH * CZ);
  for (int e = tid; e < HH * CZ; e += 256) {
    float v = pp[e] + pp[HH * CZ + e] + pp[2 * HH * CZ + e] + pp[3 * HH * CZ + e];
    cat[(size_t)i * DCAT + 576 + e] = v;
  }
  if (tid < 96) {
    int h = tid >> 3, p = tid & 7;
    const float* ob = optb + ((size_t)i * HH + h) * 24 + p * 3;
    float gx = ob[0] - T_s[0];
    float gy = ob[1] - T_s[1];
    float gz = ob[2] - T_s[2];
    float lx = R_s[0] * gx + R_s[3] * gy + R_s[6] * gz;
    float ly = R_s[1] * gx + R_s[4] * gy + R_s[7] * gz;
    float lz = R_s[2] * gx + R_s[5] * gy + R_s[8] * gz;
    float* catr = cat + (size_t)i * DCAT;
    catr[192 + 0 * 96 + h * 8 + p] = lx;
    catr[192 + 1 * 96 + h * 8 + p] = ly;
    catr[192 + 2 * 96 + h * 8 + p] = lz;
    catr[480 + h * 8 + p] = sqrtf(lx * lx + ly * ly + lz * lz + 1e-8f);
  }
}

// ---------------------------------------------------------------------------
// out_gemm: out = cat @ wout + bout  (1024 x 2112 x 384)
// ---------------------------------------------------------------------------
__global__ __launch_bounds__(256) void out_gemm(
    const float* __restrict__ cat, const float* __restrict__ wout,
    const float* __restrict__ bout, float* __restrict__ out)
{
  __shared__ float c_lds[4 * DCAT];
  const int n0 = blockIdx.x * 4;
  const int cq = blockIdx.y * 128 + (threadIdx.x & 63) * 2;
  const int rg = threadIdx.x >> 6;
  for (int idx = threadIdx.x; idx < 4 * DCAT; idx += 256) {
    int r = idx / DCAT, kk = idx - r * DCAT;
    c_lds[idx] = cat[(size_t)(n0 + r) * DCAT + kk];
  }
  __syncthreads();
  float a0 = 0.f, a1 = 0.f;
  const float* crow = &c_lds[rg * DCAT];
#pragma unroll 4
  for (int kk = 0; kk < DCAT; kk++) {
    float cv = crow[kk];
    float2 w2 = *reinterpret_cast<const float2*>(&wout[(size_t)kk * CS + cq]);
    a0 += cv * w2.x; a1 += cv * w2.y;
  }
  float* o = out + (size_t)(n0 + rg) * CS + cq;
  o[0] = a0 + bout[cq]; o[1] = a1 + bout[cq + 1];
}

// ---------------------------------------------------------------------------
extern "C" void kernel_launch(void* const* d_in, const int* in_sizes, int n_in,
                              void* d_out, int out_size, void* d_ws, size_t ws_size,
                              hipStream_t stream) {
  const float* s      = (const float*)d_in[0];
  const float* z      = (const float*)d_in[1];
  const float* rot    = (const float*)d_in[2];
  const float* trans  = (const float*)d_in[3];
  const float* mask   = (const float*)d_in[4];
  const float* wq     = (const float*)d_in[5];
  const float* bq     = (const float*)d_in[6];
  const float* wkv    = (const float*)d_in[7];
  const float* bkv    = (const float*)d_in[8];
  const float* wqp    = (const float*)d_in[9];
  const float* bqp    = (const float*)d_in[10];
  const float* wkvp   = (const float*)d_in[11];
  const float* bkvp   = (const float*)d_in[12];
  const float* wb     = (const float*)d_in[13];
  const float* bb     = (const float*)d_in[14];
  const float* head_w = (const float*)d_in[15];
  const float* wout   = (const float*)d_in[16];
  const float* bout   = (const float*)d_in[17];
  float* out = (float*)d_out;

  // workspace layout (floats; all bases 16-float aligned)
  float* ws = (float*)d_ws;
  float* proj_buf = ws;                                  // 1,179,648
  float* kc_buf   = proj_buf + (size_t)NN * PROJW;       // 196,608
  float* vc_buf   = kc_buf + (size_t)HH * 16 * NN;       // 196,608
  float* kpc_buf  = vc_buf + (size_t)HH * 16 * NN;       // 147,456
  float* vpc_buf  = kpc_buf + (size_t)HH * 12 * NN;      // 294,912
  float* knc_buf  = vpc_buf + (size_t)HH * 24 * NN;      // 12,288
  float* qpts_buf = knc_buf + (size_t)HH * NN;           // 147,456
  float* qn_buf   = qpts_buf + (size_t)NN * QPR;         // 12,288
  float* optb_buf = qn_buf + NN * HH + 16;               // 294,912
  float* cat_buf  = optb_buf + (size_t)NN * HH * 24;     // 2,162,688
  float* part_buf = cat_buf + (size_t)NN * DCAT;         // 6,291,456
  __hip_bfloat16* A_buf =
      (__hip_bfloat16*)(part_buf + (size_t)4 * NN * HH * CZ);  // 12,582,912 bf16

  proj_all<<<dim3(NN / 8, 9), dim3(256), 0, stream>>>(
      s, wq, bq, wkv, bkv, wqp, bqp, wkvp, bkvp, proj_buf);
  ipa_transform<<<dim3(NN), dim3(256), 0, stream>>>(
      proj_buf, rot, trans, kc_buf, vc_buf, qpts_buf, kpc_buf, vpc_buf,
      qn_buf, knc_buf);
  bias_pass<<<dim3(8, NN), dim3(256), 0, stream>>>(z, wb, A_buf);
  attn_logits<<<dim3(NN / 4, HH), dim3(256), 0, stream>>>(
      kc_buf, kpc_buf, knc_buf, proj_buf, qpts_buf, qn_buf,
      bb, head_w, mask, A_buf);
  attn_out<<<dim3(NN / 4, 15), dim3(256), 0, stream>>>(
      vc_buf, vpc_buf, A_buf, cat_buf, optb_buf);
  opair_pass<<<dim3(4, NN), dim3(256), 0, stream>>>(z, A_buf, part_buf);
  opair_reduce<<<dim3(NN), dim3(256), 0, stream>>>(
      part_buf, optb_buf, rot, trans, cat_buf);
  out_gemm<<<dim3(NN / 4, 3), dim3(256), 0, stream>>>(
      cat_buf, wout, bout, out);
}

// Round 16
// 658.036 us; speedup vs baseline: 1.6592x; 1.0206x over previous
//
#include <hip/hip_runtime.h>
#include <hip/hip_bf16.h>
#include <math.h>

// Problem constants
#define NN   1024
#define CS   384
#define CZ   128
#define HH   12
#define HCH  192
#define QPR  144
#define DCAT 2112
#define PROJW 1152    // 192+384+144+432
#define INF_ 100000.0f

#define SC_QK 0.14433756729740643f   // sqrt(1/48)
#define SC_B  0.5773502691896258f    // sqrt(1/3)
#define SC_PT 0.13608276348795434f   // sqrt(1/54)

__device__ __forceinline__ float dot4(float4 a, float4 b) {
  return a.x * b.x + a.y * b.y + a.z * b.z + a.w * b.w;
}
__device__ __forceinline__ float bf2f(unsigned short u) {
  unsigned int v = ((unsigned int)u) << 16;
  float f; __builtin_memcpy(&f, &v, 4); return f;
}
__device__ __forceinline__ unsigned short f2bf(float f) {
  __hip_bfloat16 h = __float2bfloat16(f);
  unsigned short u; __builtin_memcpy(&u, &h, 2); return u;
}

// ---------------------------------------------------------------------------
// proj_all: fused s @ {wq,wkv,wqp,wkvp} + bias -> proj[n][1152]
// ---------------------------------------------------------------------------
__global__ __launch_bounds__(256) void proj_all(
    const float* __restrict__ s,
    const float* __restrict__ wq, const float* __restrict__ bq,
    const float* __restrict__ wkv, const float* __restrict__ bkv,
    const float* __restrict__ wqp, const float* __restrict__ bqp,
    const float* __restrict__ wkvp, const float* __restrict__ bkvp,
    float* __restrict__ proj)
{
  __shared__ float s_lds[8 * CS];
  const int n0 = blockIdx.x * 8;
  for (int idx = threadIdx.x; idx < 8 * CS; idx += 256)
    s_lds[idx] = s[(size_t)(n0 + idx / CS) * CS + (idx % CS)];
  __syncthreads();

  const int gc = blockIdx.y * 128 + (threadIdx.x & 31) * 4;
  const int rg = threadIdx.x >> 5;
  const float* wp; const float* bp; int OUT, lc;
  if (gc < 192)      { wp = wq;   bp = bq;   OUT = 192; lc = gc; }
  else if (gc < 576) { wp = wkv;  bp = bkv;  OUT = 384; lc = gc - 192; }
  else if (gc < 720) { wp = wqp;  bp = bqp;  OUT = 144; lc = gc - 576; }
  else               { wp = wkvp; bp = bkvp; OUT = 432; lc = gc - 720; }

  float a0 = 0.f, a1 = 0.f, a2 = 0.f, a3 = 0.f;
  const float* srow = &s_lds[rg * CS];
#pragma unroll 4
  for (int kk = 0; kk < CS; kk++) {
    float sv = srow[kk];
    float4 w4 = *reinterpret_cast<const float4*>(&wp[(size_t)kk * OUT + lc]);
    a0 += sv * w4.x; a1 += sv * w4.y; a2 += sv * w4.z; a3 += sv * w4.w;
  }
  float* o = proj + (size_t)(n0 + rg) * PROJW + gc;
  o[0] = a0 + bp[lc]; o[1] = a1 + bp[lc + 1];
  o[2] = a2 + bp[lc + 2]; o[3] = a3 + bp[lc + 3];
}

// ---------------------------------------------------------------------------
// transform: split kv, rotate/translate points, write COMPONENT-MAJOR layouts
// ---------------------------------------------------------------------------
__global__ __launch_bounds__(256) void ipa_transform(
    const float* __restrict__ proj, const float* __restrict__ rot,
    const float* __restrict__ trans,
    float* __restrict__ kc, float* __restrict__ vc,
    float* __restrict__ q_pts, float* __restrict__ kpc,
    float* __restrict__ vpc, float* __restrict__ qn, float* __restrict__ knc)
{
  const int n = blockIdx.x, tid = threadIdx.x;
  const float* pr = proj + (size_t)n * PROJW;
  __shared__ float R[9], T[3], sq_q[48], sq_k[48];
  if (tid < 9) R[tid] = rot[n * 9 + tid];
  if (tid < 3) T[tid] = trans[n * 3 + tid];
  __syncthreads();
  if (tid < HCH) {
    int h = tid >> 4, c = tid & 15;
    kc[(size_t)(h * 16 + c) * NN + n] = pr[192 + h * 32 + c];
    vc[(size_t)(h * 16 + c) * NN + n] = pr[192 + h * 32 + 16 + c];
  }
  if (tid < 48) {
    float r0 = pr[576 + tid], r1 = pr[576 + 48 + tid], r2 = pr[576 + 96 + tid];
    float x = R[0] * r0 + R[1] * r1 + R[2] * r2 + T[0];
    float y = R[3] * r0 + R[4] * r1 + R[5] * r2 + T[1];
    float z = R[6] * r0 + R[7] * r1 + R[8] * r2 + T[2];
    q_pts[(size_t)n * QPR + tid * 3 + 0] = x;
    q_pts[(size_t)n * QPR + tid * 3 + 1] = y;
    q_pts[(size_t)n * QPR + tid * 3 + 2] = z;
    sq_q[tid] = x * x + y * y + z * z;
  }
  if (tid >= 64 && tid < 208) {
    int t = tid - 64;
    float r0 = pr[720 + t], r1 = pr[720 + 144 + t], r2 = pr[720 + 288 + t];
    float x = R[0] * r0 + R[1] * r1 + R[2] * r2 + T[0];
    float y = R[3] * r0 + R[4] * r1 + R[5] * r2 + T[1];
    float z = R[6] * r0 + R[7] * r1 + R[8] * r2 + T[2];
    int h = t / 12, pp = t % 12;
    if (pp < 4) {
      int d = pp * 3;
      kpc[(size_t)(h * 12 + d + 0) * NN + n] = x;
      kpc[(size_t)(h * 12 + d + 1) * NN + n] = y;
      kpc[(size_t)(h * 12 + d + 2) * NN + n] = z;
      sq_k[h * 4 + pp] = x * x + y * y + z * z;
    } else {
      int d = (pp - 4) * 3;
      vpc[(size_t)(h * 24 + d + 0) * NN + n] = x;
      vpc[(size_t)(h * 24 + d + 1) * NN + n] = y;
      vpc[(size_t)(h * 24 + d + 2) * NN + n] = z;
    }
  }
  __syncthreads();
  if (tid < HH) {
    float a = 0.f, b = 0.f;
#pragma unroll
    for (int p = 0; p < 4; p++) { a += sq_q[tid * 4 + p]; b += sq_k[tid * 4 + p]; }
    qn[n * HH + tid] = a;
    knc[(size_t)tid * NN + n] = b;
  }
}

// ---------------------------------------------------------------------------
// bias_pass: B[i,h,j] = sum_c z[i,j,c]*wb[c,h] (bf16 out). wb transposed
// in-LDS from a coalesced linear read (no prep kernel).
// ---------------------------------------------------------------------------
__global__ __launch_bounds__(256) void bias_pass(
    const float* __restrict__ z, const float* __restrict__ wb,
    __hip_bfloat16* __restrict__ B)
{
  __shared__ float wb_s[HH * CZ];      // [h][c], 6 KB
  __shared__ float bias_s[HH * 128];   // 6 KB
  const int i = blockIdx.y;
  const int jb = blockIdx.x * 128;
  const int tid = threadIdx.x;
  const int jl = tid >> 2, csub = tid & 3;

  for (int e = tid; e < HH * CZ; e += 256) {
    int c = e / HH, h = e - c * HH;     // e = c*12+h, coalesced read
    wb_s[h * CZ + c] = wb[e];
  }
  __syncthreads();

  const float* zb = z + ((size_t)i * NN + jb + jl) * CZ + csub * 4;
  float4 zq0[8], zq1[8];
#pragma unroll
  for (int k8 = 0; k8 < 8; k8++)
    zq0[k8] = *reinterpret_cast<const float4*>(&zb[k8 * 16]);
#pragma unroll
  for (int k8 = 0; k8 < 8; k8++)
    zq1[k8] = *reinterpret_cast<const float4*>(&zb[(size_t)64 * CZ + k8 * 16]);

  float bd0[HH], bd1[HH];
#pragma unroll
  for (int h = 0; h < HH; h++) { bd0[h] = 0.f; bd1[h] = 0.f; }

#pragma unroll
  for (int k8 = 0; k8 < 8; k8++) {
    const int c = csub * 4 + k8 * 16;
#pragma unroll
    for (int h = 0; h < HH; h++) {
      float4 wv = *reinterpret_cast<const float4*>(&wb_s[h * CZ + c]);
      bd0[h] += dot4(zq0[k8], wv);
      bd1[h] += dot4(zq1[k8], wv);
    }
  }
#pragma unroll
  for (int h = 0; h < HH; h++) {
    bd0[h] += __shfl_xor(bd0[h], 1); bd0[h] += __shfl_xor(bd0[h], 2);
    bd1[h] += __shfl_xor(bd1[h], 1); bd1[h] += __shfl_xor(bd1[h], 2);
  }
  if (csub == 0) {
#pragma unroll
    for (int h = 0; h < HH; h++) {
      bias_s[h * 128 + jl] = bd0[h];
      bias_s[h * 128 + 64 + jl] = bd1[h];
    }
  }
  __syncthreads();
  for (int e = tid; e < HH * 128; e += 256) {
    int h = e >> 7, j2 = e & 127;
    B[((size_t)i * HH + h) * NN + jb + j2] = __float2bfloat16(bias_s[e]);
  }
}

// ---------------------------------------------------------------------------
// attn_logits: logits + row softmax -> normalized A (bf16), one WARP per
// (i,h). grid (NN/4, HH). Natural register allocation.
// ---------------------------------------------------------------------------
__global__ __launch_bounds__(256) void attn_logits(
    const float* __restrict__ kc, const float* __restrict__ kpc,
    const float* __restrict__ knc, const float* __restrict__ proj,
    const float* __restrict__ q_pts, const float* __restrict__ qn,
    const float* __restrict__ bb, const float* __restrict__ head_w,
    const float* __restrict__ mask, __hip_bfloat16* __restrict__ A)
{
  const int h = blockIdx.y;
  const int i = blockIdx.x * 4 + (threadIdx.x >> 6);
  const int lane = threadIdx.x & 63;

  const float* qb = proj + (size_t)i * PROJW + h * 16;
  const float4 q0 = *reinterpret_cast<const float4*>(qb);
  const float4 q1 = *reinterpret_cast<const float4*>(qb + 4);
  const float4 q2 = *reinterpret_cast<const float4*>(qb + 8);
  const float4 q3 = *reinterpret_cast<const float4*>(qb + 12);
  const float* pb = q_pts + (size_t)i * QPR + h * 12;
  const float4 p0 = *reinterpret_cast<const float4*>(pb);
  const float4 p1 = *reinterpret_cast<const float4*>(pb + 4);
  const float4 p2 = *reinterpret_cast<const float4*>(pb + 8);
  const float qnv = qn[i * HH + h];
  const float bbv = bb[h];
  const float xw = head_w[h];
  const float hwv = ((xw > 20.f) ? xw : log1pf(__expf(xw))) * SC_PT;
  const float mi = mask[i];

  const float* kch  = kc  + (size_t)h * 16 * NN;
  const float* kpch = kpc + (size_t)h * 12 * NN;
  const float* knch = knc + (size_t)h * NN;
  __hip_bfloat16* Arow = A + ((size_t)i * HH + h) * NN;

  float4 av[4];
#pragma unroll
  for (int t = 0; t < 4; t++) {
    const int j = t * 256 + lane * 4;
    float4 d = {0, 0, 0, 0};
#pragma unroll
    for (int c = 0; c < 16; c++) {
      const float qc = (c < 4 ? (&q0.x)[c] : c < 8 ? (&q1.x)[c - 4]
                       : c < 12 ? (&q2.x)[c - 8] : (&q3.x)[c - 12]);
      float4 kv = *reinterpret_cast<const float4*>(&kch[(size_t)c * NN + j]);
      d.x += qc * kv.x; d.y += qc * kv.y; d.z += qc * kv.z; d.w += qc * kv.w;
    }
    float4 cr = {0, 0, 0, 0};
#pragma unroll
    for (int dd = 0; dd < 12; dd++) {
      const float pc = (dd < 4 ? (&p0.x)[dd] : dd < 8 ? (&p1.x)[dd - 4]
                        : (&p2.x)[dd - 8]);
      float4 kv = *reinterpret_cast<const float4*>(&kpch[(size_t)dd * NN + j]);
      cr.x += pc * kv.x; cr.y += pc * kv.y; cr.z += pc * kv.z; cr.w += pc * kv.w;
    }
    float4 kn4 = *reinterpret_cast<const float4*>(&knch[j]);
    ushort4 bu = *reinterpret_cast<const ushort4*>(&Arow[j]);
    float4 m4 = *reinterpret_cast<const float4*>(&mask[j]);
    av[t].x = SC_QK * d.x + SC_B * (bf2f(bu.x) + bbv)
              - 0.5f * hwv * (qnv + kn4.x - 2.f * cr.x) + INF_ * (mi * m4.x - 1.f);
    av[t].y = SC_QK * d.y + SC_B * (bf2f(bu.y) + bbv)
              - 0.5f * hwv * (qnv + kn4.y - 2.f * cr.y) + INF_ * (mi * m4.y - 1.f);
    av[t].z = SC_QK * d.z + SC_B * (bf2f(bu.z) + bbv)
              - 0.5f * hwv * (qnv + kn4.z - 2.f * cr.z) + INF_ * (mi * m4.z - 1.f);
    av[t].w = SC_QK * d.w + SC_B * (bf2f(bu.w) + bbv)
              - 0.5f * hwv * (qnv + kn4.w - 2.f * cr.w) + INF_ * (mi * m4.w - 1.f);
  }

  float m = av[0].x;
#pragma unroll
  for (int t = 0; t < 4; t++) {
    m = fmaxf(m, av[t].x); m = fmaxf(m, av[t].y);
    m = fmaxf(m, av[t].z); m = fmaxf(m, av[t].w);
  }
  for (int off = 32; off; off >>= 1) m = fmaxf(m, __shfl_xor(m, off));
  float ssum = 0.f;
#pragma unroll
  for (int t = 0; t < 4; t++) {
    av[t].x = __expf(av[t].x - m); ssum += av[t].x;
    av[t].y = __expf(av[t].y - m); ssum += av[t].y;
    av[t].z = __expf(av[t].z - m); ssum += av[t].z;
    av[t].w = __expf(av[t].w - m); ssum += av[t].w;
  }
  for (int off = 32; off; off >>= 1) ssum += __shfl_xor(ssum, off);
  const float inv = 1.f / ssum;
#pragma unroll
  for (int t = 0; t < 4; t++) {
    const int j = t * 256 + lane * 4;
    ushort4 st;
    st.x = f2bf(av[t].x * inv); st.y = f2bf(av[t].y * inv);
    st.z = f2bf(av[t].z * inv); st.w = f2bf(av[t].w * inv);
    *reinterpret_cast<ushort4*>(&Arow[j]) = st;
  }
}

// ---------------------------------------------------------------------------
// attn_out v2 (round-15 winner): task-grouped + i-batched.
// Warp = (task t, 4 consecutive i); t: h = t/5, grp = t%5 -> 8 components.
// grid (NN/4, 15), block 256.
// ---------------------------------------------------------------------------
__global__ __launch_bounds__(256) void attn_out(
    const float* __restrict__ vc, const float* __restrict__ vpc,
    const __hip_bfloat16* __restrict__ A,
    float* __restrict__ cat, float* __restrict__ optb)
{
  const int w = threadIdx.x >> 6, lane = threadIdx.x & 63;
  const int t = blockIdx.y * 4 + w;
  const int h = t / 5, grp = t - h * 5;
  const int i0 = blockIdx.x * 4;

  const float* base = (grp < 2)
      ? vc + (size_t)(h * 16 + grp * 8) * NN
      : vpc + (size_t)(h * 24 + (grp - 2) * 8) * NN;
  const unsigned short* A0 = reinterpret_cast<const unsigned short*>(A)
                             + ((size_t)i0 * HH + h) * NN;
  const unsigned short* A1 = A0 + (size_t)HH * NN;
  const unsigned short* A2 = A1 + (size_t)HH * NN;
  const unsigned short* A3 = A2 + (size_t)HH * NN;

  float acc0[8], acc1[8], acc2[8], acc3[8];
#pragma unroll
  for (int r = 0; r < 8; r++) { acc0[r] = 0.f; acc1[r] = 0.f; acc2[r] = 0.f; acc3[r] = 0.f; }

#pragma unroll 2
  for (int it = 0; it < 16; it++) {
    const int j = it * 64 + lane;
    float vv[8];
#pragma unroll
    for (int r = 0; r < 8; r++) vv[r] = base[(size_t)r * NN + j];
    const float a0 = bf2f(A0[j]);
    const float a1 = bf2f(A1[j]);
    const float a2 = bf2f(A2[j]);
    const float a3 = bf2f(A3[j]);
#pragma unroll
    for (int r = 0; r < 8; r++) {
      acc0[r] += a0 * vv[r];
      acc1[r] += a1 * vv[r];
      acc2[r] += a2 * vv[r];
      acc3[r] += a3 * vv[r];
    }
  }
  for (int off = 32; off; off >>= 1) {
#pragma unroll
    for (int r = 0; r < 8; r++) {
      acc0[r] += __shfl_xor(acc0[r], off);
      acc1[r] += __shfl_xor(acc1[r], off);
      acc2[r] += __shfl_xor(acc2[r], off);
      acc3[r] += __shfl_xor(acc3[r], off);
    }
  }
  if (lane == 0) {
    if (grp < 2) {
      const int co = h * 16 + grp * 8;
      float* c0 = cat + (size_t)(i0 + 0) * DCAT + co;
      float* c1 = cat + (size_t)(i0 + 1) * DCAT + co;
      float* c2 = cat + (size_t)(i0 + 2) * DCAT + co;
      float* c3 = cat + (size_t)(i0 + 3) * DCAT + co;
#pragma unroll
      for (int r = 0; r < 8; r++) {
        c0[r] = acc0[r]; c1[r] = acc1[r]; c2[r] = acc2[r]; c3[r] = acc3[r];
      }
    } else {
      const int doff = (grp - 2) * 8;
      float* o0 = optb + ((size_t)(i0 + 0) * HH + h) * 24 + doff;
      float* o1 = optb + ((size_t)(i0 + 1) * HH + h) * 24 + doff;
      float* o2 = optb + ((size_t)(i0 + 2) * HH + h) * 24 + doff;
      float* o3 = optb + ((size_t)(i0 + 3) * HH + h) * 24 + doff;
#pragma unroll
      for (int r = 0; r < 8; r++) {
        o0[r] = acc0[r]; o1[r] = acc1[r]; o2[r] = acc2[r]; o3[r] = acc3[r];
      }
    }
  }
}

// ---------------------------------------------------------------------------
// opair_pass: split-j partial o_pair. grid (4, 1024).
// i REVERSED (isolated change): first blocks read the z tail still L3-hot
// from bias_pass.
// ---------------------------------------------------------------------------
__global__ __launch_bounds__(256) void opair_pass(
    const float* __restrict__ z, const __hip_bfloat16* __restrict__ A,
    float* __restrict__ partial)
{
  __shared__ float A_ls[256 * HH];  // 12 KB, [jloc][h]
  __shared__ float red[HH * CZ];    // 6 KB
  const int sp = blockIdx.x, i = NN - 1 - blockIdx.y;
  const int jb = sp * 256;
  const int tid = threadIdx.x;
  const int c4 = (tid & 31) * 4, jsub = tid >> 5;

  for (int e = tid; e < HH * 64; e += 256) {
    int h = e >> 6, j4 = (e & 63) * 4;
    ushort4 au = *reinterpret_cast<const ushort4*>(
        &A[((size_t)i * HH + h) * NN + jb + j4]);
    A_ls[(j4 + 0) * HH + h] = bf2f(au.x);
    A_ls[(j4 + 1) * HH + h] = bf2f(au.y);
    A_ls[(j4 + 2) * HH + h] = bf2f(au.z);
    A_ls[(j4 + 3) * HH + h] = bf2f(au.w);
  }
  for (int e = tid; e < HH * CZ; e += 256) red[e] = 0.f;
  __syncthreads();

  float4 acc[HH];
#pragma unroll
  for (int h = 0; h < HH; h++) acc[h] = make_float4(0.f, 0.f, 0.f, 0.f);

  const float* zrow = z + ((size_t)i * NN + jb + jsub * 32) * CZ + c4;
  const float* arow = &A_ls[jsub * 32 * HH];
  for (int j0 = 0; j0 < 32; j0 += 4) {
#pragma unroll
    for (int jj = 0; jj < 4; jj++) {
      const int j = j0 + jj;
      float4 zq = *reinterpret_cast<const float4*>(&zrow[(size_t)j * CZ]);
      float4 a0 = *reinterpret_cast<const float4*>(&arow[j * HH]);
      float4 a1 = *reinterpret_cast<const float4*>(&arow[j * HH + 4]);
      float4 a2 = *reinterpret_cast<const float4*>(&arow[j * HH + 8]);
      acc[0].x += a0.x * zq.x; acc[0].y += a0.x * zq.y;
      acc[0].z += a0.x * zq.z; acc[0].w += a0.x * zq.w;
      acc[1].x += a0.y * zq.x; acc[1].y += a0.y * zq.y;
      acc[1].z += a0.y * zq.z; acc[1].w += a0.y * zq.w;
      acc[2].x += a0.z * zq.x; acc[2].y += a0.z * zq.y;
      acc[2].z += a0.z * zq.z; acc[2].w += a0.z * zq.w;
      acc[3].x += a0.w * zq.x; acc[3].y += a0.w * zq.y;
      acc[3].z += a0.w * zq.z; acc[3].w += a0.w * zq.w;
      acc[4].x += a1.x * zq.x; acc[4].y += a1.x * zq.y;
      acc[4].z += a1.x * zq.z; acc[4].w += a1.x * zq.w;
      acc[5].x += a1.y * zq.x; acc[5].y += a1.y * zq.y;
      acc[5].z += a1.y * zq.z; acc[5].w += a1.y * zq.w;
      acc[6].x += a1.z * zq.x; acc[6].y += a1.z * zq.y;
      acc[6].z += a1.z * zq.z; acc[6].w += a1.z * zq.w;
      acc[7].x += a1.w * zq.x; acc[7].y += a1.w * zq.y;
      acc[7].z += a1.w * zq.z; acc[7].w += a1.w * zq.w;
      acc[8].x += a2.x * zq.x; acc[8].y += a2.x * zq.y;
      acc[8].z += a2.x * zq.z; acc[8].w += a2.x * zq.w;
      acc[9].x += a2.y * zq.x; acc[9].y += a2.y * zq.y;
      acc[9].z += a2.y * zq.z; acc[9].w += a2.y * zq.w;
      acc[10].x += a2.z * zq.x; acc[10].y += a2.z * zq.y;
      acc[10].z += a2.z * zq.z; acc[10].w += a2.z * zq.w;
      acc[11].x += a2.w * zq.x; acc[11].y += a2.w * zq.y;
      acc[11].z += a2.w * zq.z; acc[11].w += a2.w * zq.w;
    }
  }
  for (int s = 0; s < 8; s++) {
    __syncthreads();
    if (jsub == s) {
#pragma unroll
      for (int h = 0; h < HH; h++) {
        red[h * CZ + c4 + 0] += acc[h].x;
        red[h * CZ + c4 + 1] += acc[h].y;
        red[h * CZ + c4 + 2] += acc[h].z;
        red[h * CZ + c4 + 3] += acc[h].w;
      }
    }
  }
  __syncthreads();
  float* pp = partial + ((size_t)(i * 4 + sp)) * (HH * CZ);
  for (int e = tid; e < HH * CZ; e += 256) pp[e] = red[e];
}

// ---------------------------------------------------------------------------
// opair_reduce (+fused finish): sum 4 partials -> cat[576:2112];
// inverse-rotate o_pt + norms -> cat[192:576]. grid NN, block 256.
// ---------------------------------------------------------------------------
__global__ __launch_bounds__(256) void opair_reduce(
    const float* __restrict__ partial, const float* __restrict__ optb,
    const float* __restrict__ rot, const float* __restrict__ trans,
    float* __restrict__ cat)
{
  const int i = blockIdx.x, tid = threadIdx.x;
  __shared__ float R_s[9], T_s[3];
  if (tid < 9) R_s[tid] = rot[i * 9 + tid];
  if (tid < 3) T_s[tid] = trans[i * 3 + tid];
  __syncthreads();

  const float* pp = partial + ((size_t)i * 4) * (HH * CZ);
  for (int e = tid; e < HH * CZ; e += 256) {
    float v = pp[e] + pp[HH * CZ + e] + pp[2 * HH * CZ + e] + pp[3 * HH * CZ + e];
    cat[(size_t)i * DCAT + 576 + e] = v;
  }
  if (tid < 96) {
    int h = tid >> 3, p = tid & 7;
    const float* ob = optb + ((size_t)i * HH + h) * 24 + p * 3;
    float gx = ob[0] - T_s[0];
    float gy = ob[1] - T_s[1];
    float gz = ob[2] - T_s[2];
    float lx = R_s[0] * gx + R_s[3] * gy + R_s[6] * gz;
    float ly = R_s[1] * gx + R_s[4] * gy + R_s[7] * gz;
    float lz = R_s[2] * gx + R_s[5] * gy + R_s[8] * gz;
    float* catr = cat + (size_t)i * DCAT;
    catr[192 + 0 * 96 + h * 8 + p] = lx;
    catr[192 + 1 * 96 + h * 8 + p] = ly;
    catr[192 + 2 * 96 + h * 8 + p] = lz;
    catr[480 + h * 8 + p] = sqrtf(lx * lx + ly * ly + lz * lz + 1e-8f);
  }
}

// ---------------------------------------------------------------------------
// out_gemm v3: out = cat @ wout + bout (1024 x 2112 x 384).
// 8 rows/block, K-tiled (OKT=528, LDS 16.9 KB) -> grid.x halves -> wout
// logical traffic 830 -> 415 MB. grid (128, 3), block 256.
// ---------------------------------------------------------------------------
#define OKT 528
__global__ __launch_bounds__(256) void out_gemm(
    const float* __restrict__ cat, const float* __restrict__ wout,
    const float* __restrict__ bout, float* __restrict__ out)
{
  __shared__ float c_lds[8 * OKT];   // 16.9 KB
  const int n0 = blockIdx.x * 8;
  const int cq = blockIdx.y * 128 + (threadIdx.x & 31) * 4;
  const int rg = threadIdx.x >> 5;
  float a0 = 0.f, a1 = 0.f, a2 = 0.f, a3 = 0.f;

  for (int kc = 0; kc < DCAT / OKT; kc++) {
    __syncthreads();
    for (int idx = threadIdx.x; idx < 8 * OKT; idx += 256) {
      int r = idx / OKT, kk = idx - r * OKT;
      c_lds[idx] = cat[(size_t)(n0 + r) * DCAT + kc * OKT + kk];
    }
    __syncthreads();
    const float* crow = &c_lds[rg * OKT];
#pragma unroll 4
    for (int kk = 0; kk < OKT; kk++) {
      float cv = crow[kk];
      float4 w4 = *reinterpret_cast<const float4*>(
          &wout[(size_t)(kc * OKT + kk) * CS + cq]);
      a0 += cv * w4.x; a1 += cv * w4.y; a2 += cv * w4.z; a3 += cv * w4.w;
    }
  }
  float* o = out + (size_t)(n0 + rg) * CS + cq;
  o[0] = a0 + bout[cq]; o[1] = a1 + bout[cq + 1];
  o[2] = a2 + bout[cq + 2]; o[3] = a3 + bout[cq + 3];
}

// ---------------------------------------------------------------------------
extern "C" void kernel_launch(void* const* d_in, const int* in_sizes, int n_in,
                              void* d_out, int out_size, void* d_ws, size_t ws_size,
                              hipStream_t stream) {
  const float* s      = (const float*)d_in[0];
  const float* z      = (const float*)d_in[1];
  const float* rot    = (const float*)d_in[2];
  const float* trans  = (const float*)d_in[3];
  const float* mask   = (const float*)d_in[4];
  const float* wq     = (const float*)d_in[5];
  const float* bq     = (const float*)d_in[6];
  const float* wkv    = (const float*)d_in[7];
  const float* bkv    = (const float*)d_in[8];
  const float* wqp    = (const float*)d_in[9];
  const float* bqp    = (const float*)d_in[10];
  const float* wkvp   = (const float*)d_in[11];
  const float* bkvp   = (const float*)d_in[12];
  const float* wb     = (const float*)d_in[13];
  const float* bb     = (const float*)d_in[14];
  const float* head_w = (const float*)d_in[15];
  const float* wout   = (const float*)d_in[16];
  const float* bout   = (const float*)d_in[17];
  float* out = (float*)d_out;

  // workspace layout (floats; all bases 16-float aligned)
  float* ws = (float*)d_ws;
  float* proj_buf = ws;                                  // 1,179,648
  float* kc_buf   = proj_buf + (size_t)NN * PROJW;       // 196,608
  float* vc_buf   = kc_buf + (size_t)HH * 16 * NN;       // 196,608
  float* kpc_buf  = vc_buf + (size_t)HH * 16 * NN;       // 147,456
  float* vpc_buf  = kpc_buf + (size_t)HH * 12 * NN;      // 294,912
  float* knc_buf  = vpc_buf + (size_t)HH * 24 * NN;      // 12,288
  float* qpts_buf = knc_buf + (size_t)HH * NN;           // 147,456
  float* qn_buf   = qpts_buf + (size_t)NN * QPR;         // 12,288
  float* optb_buf = qn_buf + NN * HH + 16;               // 294,912
  float* cat_buf  = optb_buf + (size_t)NN * HH * 24;     // 2,162,688
  float* part_buf = cat_buf + (size_t)NN * DCAT;         // 6,291,456
  __hip_bfloat16* A_buf =
      (__hip_bfloat16*)(part_buf + (size_t)4 * NN * HH * CZ);  // 12,582,912 bf16

  proj_all<<<dim3(NN / 8, 9), dim3(256), 0, stream>>>(
      s, wq, bq, wkv, bkv, wqp, bqp, wkvp, bkvp, proj_buf);
  ipa_transform<<<dim3(NN), dim3(256), 0, stream>>>(
      proj_buf, rot, trans, kc_buf, vc_buf, qpts_buf, kpc_buf, vpc_buf,
      qn_buf, knc_buf);
  bias_pass<<<dim3(8, NN), dim3(256), 0, stream>>>(z, wb, A_buf);
  attn_logits<<<dim3(NN / 4, HH), dim3(256), 0, stream>>>(
      kc_buf, kpc_buf, knc_buf, proj_buf, qpts_buf, qn_buf,
      bb, head_w, mask, A_buf);
  attn_out<<<dim3(NN / 4, 15), dim3(256), 0, stream>>>(
      vc_buf, vpc_buf, A_buf, cat_buf, optb_buf);
  opair_pass<<<dim3(4, NN), dim3(256), 0, stream>>>(z, A_buf, part_buf);
  opair_reduce<<<dim3(NN), dim3(256), 0, stream>>>(
      part_buf, optb_buf, rot, trans, cat_buf);
  out_gemm<<<dim3(NN / 8, 3), dim3(256), 0, stream>>>(
      cat_buf, wout, bout, out);
}

// Round 17
// 656.155 us; speedup vs baseline: 1.6639x; 1.0029x over previous
//
#include <hip/hip_runtime.h>
#include <hip/hip_bf16.h>
#include <math.h>

// Problem constants
#define NN   1024
#define CS   384
#define CZ   128
#define HH   12
#define HCH  192
#define QPR  144
#define DCAT 2112
#define PROJW 1152    // 192+384+144+432
#define INF_ 100000.0f

#define SC_QK 0.14433756729740643f   // sqrt(1/48)
#define SC_B  0.5773502691896258f    // sqrt(1/3)
#define SC_PT 0.13608276348795434f   // sqrt(1/54)

__device__ __forceinline__ float dot4(float4 a, float4 b) {
  return a.x * b.x + a.y * b.y + a.z * b.z + a.w * b.w;
}
__device__ __forceinline__ float bf2f(unsigned short u) {
  unsigned int v = ((unsigned int)u) << 16;
  float f; __builtin_memcpy(&f, &v, 4); return f;
}
__device__ __forceinline__ unsigned short f2bf(float f) {
  __hip_bfloat16 h = __float2bfloat16(f);
  unsigned short u; __builtin_memcpy(&u, &h, 2); return u;
}

// ---------------------------------------------------------------------------
// proj_all: fused s @ {wq,wkv,wqp,wkvp} + bias -> proj[n][1152]
// ---------------------------------------------------------------------------
__global__ __launch_bounds__(256) void proj_all(
    const float* __restrict__ s,
    const float* __restrict__ wq, const float* __restrict__ bq,
    const float* __restrict__ wkv, const float* __restrict__ bkv,
    const float* __restrict__ wqp, const float* __restrict__ bqp,
    const float* __restrict__ wkvp, const float* __restrict__ bkvp,
    float* __restrict__ proj)
{
  __shared__ float s_lds[8 * CS];
  const int n0 = blockIdx.x * 8;
  for (int idx = threadIdx.x; idx < 8 * CS; idx += 256)
    s_lds[idx] = s[(size_t)(n0 + idx / CS) * CS + (idx % CS)];
  __syncthreads();

  const int gc = blockIdx.y * 128 + (threadIdx.x & 31) * 4;
  const int rg = threadIdx.x >> 5;
  const float* wp; const float* bp; int OUT, lc;
  if (gc < 192)      { wp = wq;   bp = bq;   OUT = 192; lc = gc; }
  else if (gc < 576) { wp = wkv;  bp = bkv;  OUT = 384; lc = gc - 192; }
  else if (gc < 720) { wp = wqp;  bp = bqp;  OUT = 144; lc = gc - 576; }
  else               { wp = wkvp; bp = bkvp; OUT = 432; lc = gc - 720; }

  float a0 = 0.f, a1 = 0.f, a2 = 0.f, a3 = 0.f;
  const float* srow = &s_lds[rg * CS];
#pragma unroll 4
  for (int kk = 0; kk < CS; kk++) {
    float sv = srow[kk];
    float4 w4 = *reinterpret_cast<const float4*>(&wp[(size_t)kk * OUT + lc]);
    a0 += sv * w4.x; a1 += sv * w4.y; a2 += sv * w4.z; a3 += sv * w4.w;
  }
  float* o = proj + (size_t)(n0 + rg) * PROJW + gc;
  o[0] = a0 + bp[lc]; o[1] = a1 + bp[lc + 1];
  o[2] = a2 + bp[lc + 2]; o[3] = a3 + bp[lc + 3];
}

// ---------------------------------------------------------------------------
// transform: split kv, rotate/translate points, write COMPONENT-MAJOR layouts
// ---------------------------------------------------------------------------
__global__ __launch_bounds__(256) void ipa_transform(
    const float* __restrict__ proj, const float* __restrict__ rot,
    const float* __restrict__ trans,
    float* __restrict__ kc, float* __restrict__ vc,
    float* __restrict__ q_pts, float* __restrict__ kpc,
    float* __restrict__ vpc, float* __restrict__ qn, float* __restrict__ knc)
{
  const int n = blockIdx.x, tid = threadIdx.x;
  const float* pr = proj + (size_t)n * PROJW;
  __shared__ float R[9], T[3], sq_q[48], sq_k[48];
  if (tid < 9) R[tid] = rot[n * 9 + tid];
  if (tid < 3) T[tid] = trans[n * 3 + tid];
  __syncthreads();
  if (tid < HCH) {
    int h = tid >> 4, c = tid & 15;
    kc[(size_t)(h * 16 + c) * NN + n] = pr[192 + h * 32 + c];
    vc[(size_t)(h * 16 + c) * NN + n] = pr[192 + h * 32 + 16 + c];
  }
  if (tid < 48) {
    float r0 = pr[576 + tid], r1 = pr[576 + 48 + tid], r2 = pr[576 + 96 + tid];
    float x = R[0] * r0 + R[1] * r1 + R[2] * r2 + T[0];
    float y = R[3] * r0 + R[4] * r1 + R[5] * r2 + T[1];
    float z = R[6] * r0 + R[7] * r1 + R[8] * r2 + T[2];
    q_pts[(size_t)n * QPR + tid * 3 + 0] = x;
    q_pts[(size_t)n * QPR + tid * 3 + 1] = y;
    q_pts[(size_t)n * QPR + tid * 3 + 2] = z;
    sq_q[tid] = x * x + y * y + z * z;
  }
  if (tid >= 64 && tid < 208) {
    int t = tid - 64;
    float r0 = pr[720 + t], r1 = pr[720 + 144 + t], r2 = pr[720 + 288 + t];
    float x = R[0] * r0 + R[1] * r1 + R[2] * r2 + T[0];
    float y = R[3] * r0 + R[4] * r1 + R[5] * r2 + T[1];
    float z = R[6] * r0 + R[7] * r1 + R[8] * r2 + T[2];
    int h = t / 12, pp = t % 12;
    if (pp < 4) {
      int d = pp * 3;
      kpc[(size_t)(h * 12 + d + 0) * NN + n] = x;
      kpc[(size_t)(h * 12 + d + 1) * NN + n] = y;
      kpc[(size_t)(h * 12 + d + 2) * NN + n] = z;
      sq_k[h * 4 + pp] = x * x + y * y + z * z;
    } else {
      int d = (pp - 4) * 3;
      vpc[(size_t)(h * 24 + d + 0) * NN + n] = x;
      vpc[(size_t)(h * 24 + d + 1) * NN + n] = y;
      vpc[(size_t)(h * 24 + d + 2) * NN + n] = z;
    }
  }
  __syncthreads();
  if (tid < HH) {
    float a = 0.f, b = 0.f;
#pragma unroll
    for (int p = 0; p < 4; p++) { a += sq_q[tid * 4 + p]; b += sq_k[tid * 4 + p]; }
    qn[n * HH + tid] = a;
    knc[(size_t)tid * NN + n] = b;
  }
}

// ---------------------------------------------------------------------------
// bias_pass: B[i,h,j] = sum_c z[i,j,c]*wb[c,h] (bf16 out). wb transposed
// in-LDS from a coalesced linear read (no prep kernel).
// ---------------------------------------------------------------------------
__global__ __launch_bounds__(256) void bias_pass(
    const float* __restrict__ z, const float* __restrict__ wb,
    __hip_bfloat16* __restrict__ B)
{
  __shared__ float wb_s[HH * CZ];      // [h][c], 6 KB
  __shared__ float bias_s[HH * 128];   // 6 KB
  const int i = blockIdx.y;
  const int jb = blockIdx.x * 128;
  const int tid = threadIdx.x;
  const int jl = tid >> 2, csub = tid & 3;

  for (int e = tid; e < HH * CZ; e += 256) {
    int c = e / HH, h = e - c * HH;     // e = c*12+h, coalesced read
    wb_s[h * CZ + c] = wb[e];
  }
  __syncthreads();

  const float* zb = z + ((size_t)i * NN + jb + jl) * CZ + csub * 4;
  float4 zq0[8], zq1[8];
#pragma unroll
  for (int k8 = 0; k8 < 8; k8++)
    zq0[k8] = *reinterpret_cast<const float4*>(&zb[k8 * 16]);
#pragma unroll
  for (int k8 = 0; k8 < 8; k8++)
    zq1[k8] = *reinterpret_cast<const float4*>(&zb[(size_t)64 * CZ + k8 * 16]);

  float bd0[HH], bd1[HH];
#pragma unroll
  for (int h = 0; h < HH; h++) { bd0[h] = 0.f; bd1[h] = 0.f; }

#pragma unroll
  for (int k8 = 0; k8 < 8; k8++) {
    const int c = csub * 4 + k8 * 16;
#pragma unroll
    for (int h = 0; h < HH; h++) {
      float4 wv = *reinterpret_cast<const float4*>(&wb_s[h * CZ + c]);
      bd0[h] += dot4(zq0[k8], wv);
      bd1[h] += dot4(zq1[k8], wv);
    }
  }
#pragma unroll
  for (int h = 0; h < HH; h++) {
    bd0[h] += __shfl_xor(bd0[h], 1); bd0[h] += __shfl_xor(bd0[h], 2);
    bd1[h] += __shfl_xor(bd1[h], 1); bd1[h] += __shfl_xor(bd1[h], 2);
  }
  if (csub == 0) {
#pragma unroll
    for (int h = 0; h < HH; h++) {
      bias_s[h * 128 + jl] = bd0[h];
      bias_s[h * 128 + 64 + jl] = bd1[h];
    }
  }
  __syncthreads();
  for (int e = tid; e < HH * 128; e += 256) {
    int h = e >> 7, j2 = e & 127;
    B[((size_t)i * HH + h) * NN + jb + j2] = __float2bfloat16(bias_s[e]);
  }
}

// ---------------------------------------------------------------------------
// attn_logits: logits + row softmax -> normalized A (bf16), one WARP per
// (i,h). grid (NN/4, HH). kn/bias/mask for all 4 t-tiles prefetched up front
// (removes the dependency-tail stall; VGPR target <=128).
// ---------------------------------------------------------------------------
__global__ __launch_bounds__(256) void attn_logits(
    const float* __restrict__ kc, const float* __restrict__ kpc,
    const float* __restrict__ knc, const float* __restrict__ proj,
    const float* __restrict__ q_pts, const float* __restrict__ qn,
    const float* __restrict__ bb, const float* __restrict__ head_w,
    const float* __restrict__ mask, __hip_bfloat16* __restrict__ A)
{
  const int h = blockIdx.y;
  const int i = blockIdx.x * 4 + (threadIdx.x >> 6);
  const int lane = threadIdx.x & 63;

  const float* qb = proj + (size_t)i * PROJW + h * 16;
  const float4 q0 = *reinterpret_cast<const float4*>(qb);
  const float4 q1 = *reinterpret_cast<const float4*>(qb + 4);
  const float4 q2 = *reinterpret_cast<const float4*>(qb + 8);
  const float4 q3 = *reinterpret_cast<const float4*>(qb + 12);
  const float* pb = q_pts + (size_t)i * QPR + h * 12;
  const float4 p0 = *reinterpret_cast<const float4*>(pb);
  const float4 p1 = *reinterpret_cast<const float4*>(pb + 4);
  const float4 p2 = *reinterpret_cast<const float4*>(pb + 8);
  const float qnv = qn[i * HH + h];
  const float bbv = bb[h];
  const float xw = head_w[h];
  const float hwv = ((xw > 20.f) ? xw : log1pf(__expf(xw))) * SC_PT;
  const float mi = mask[i];

  const float* kch  = kc  + (size_t)h * 16 * NN;
  const float* kpch = kpc + (size_t)h * 12 * NN;
  const float* knch = knc + (size_t)h * NN;
  __hip_bfloat16* Arow = A + ((size_t)i * HH + h) * NN;

  // prefetch the per-tile tail operands for all 4 tiles
  float4 kn4b[4], m4b[4];
  ushort4 bub[4];
#pragma unroll
  for (int t = 0; t < 4; t++) {
    const int j = t * 256 + lane * 4;
    kn4b[t] = *reinterpret_cast<const float4*>(&knch[j]);
    bub[t]  = *reinterpret_cast<const ushort4*>(&Arow[j]);
    m4b[t]  = *reinterpret_cast<const float4*>(&mask[j]);
  }

  float4 av[4];
#pragma unroll
  for (int t = 0; t < 4; t++) {
    const int j = t * 256 + lane * 4;
    float4 d = {0, 0, 0, 0};
#pragma unroll
    for (int c = 0; c < 16; c++) {
      const float qc = (c < 4 ? (&q0.x)[c] : c < 8 ? (&q1.x)[c - 4]
                       : c < 12 ? (&q2.x)[c - 8] : (&q3.x)[c - 12]);
      float4 kv = *reinterpret_cast<const float4*>(&kch[(size_t)c * NN + j]);
      d.x += qc * kv.x; d.y += qc * kv.y; d.z += qc * kv.z; d.w += qc * kv.w;
    }
    float4 cr = {0, 0, 0, 0};
#pragma unroll
    for (int dd = 0; dd < 12; dd++) {
      const float pc = (dd < 4 ? (&p0.x)[dd] : dd < 8 ? (&p1.x)[dd - 4]
                        : (&p2.x)[dd - 8]);
      float4 kv = *reinterpret_cast<const float4*>(&kpch[(size_t)dd * NN + j]);
      cr.x += pc * kv.x; cr.y += pc * kv.y; cr.z += pc * kv.z; cr.w += pc * kv.w;
    }
    const float4 kn4 = kn4b[t];
    const ushort4 bu = bub[t];
    const float4 m4 = m4b[t];
    av[t].x = SC_QK * d.x + SC_B * (bf2f(bu.x) + bbv)
              - 0.5f * hwv * (qnv + kn4.x - 2.f * cr.x) + INF_ * (mi * m4.x - 1.f);
    av[t].y = SC_QK * d.y + SC_B * (bf2f(bu.y) + bbv)
              - 0.5f * hwv * (qnv + kn4.y - 2.f * cr.y) + INF_ * (mi * m4.y - 1.f);
    av[t].z = SC_QK * d.z + SC_B * (bf2f(bu.z) + bbv)
              - 0.5f * hwv * (qnv + kn4.z - 2.f * cr.z) + INF_ * (mi * m4.z - 1.f);
    av[t].w = SC_QK * d.w + SC_B * (bf2f(bu.w) + bbv)
              - 0.5f * hwv * (qnv + kn4.w - 2.f * cr.w) + INF_ * (mi * m4.w - 1.f);
  }

  float m = av[0].x;
#pragma unroll
  for (int t = 0; t < 4; t++) {
    m = fmaxf(m, av[t].x); m = fmaxf(m, av[t].y);
    m = fmaxf(m, av[t].z); m = fmaxf(m, av[t].w);
  }
  for (int off = 32; off; off >>= 1) m = fmaxf(m, __shfl_xor(m, off));
  float ssum = 0.f;
#pragma unroll
  for (int t = 0; t < 4; t++) {
    av[t].x = __expf(av[t].x - m); ssum += av[t].x;
    av[t].y = __expf(av[t].y - m); ssum += av[t].y;
    av[t].z = __expf(av[t].z - m); ssum += av[t].z;
    av[t].w = __expf(av[t].w - m); ssum += av[t].w;
  }
  for (int off = 32; off; off >>= 1) ssum += __shfl_xor(ssum, off);
  const float inv = 1.f / ssum;
#pragma unroll
  for (int t = 0; t < 4; t++) {
    const int j = t * 256 + lane * 4;
    ushort4 st;
    st.x = f2bf(av[t].x * inv); st.y = f2bf(av[t].y * inv);
    st.z = f2bf(av[t].z * inv); st.w = f2bf(av[t].w * inv);
    *reinterpret_cast<ushort4*>(&Arow[j]) = st;
  }
}

// ---------------------------------------------------------------------------
// attn_out v2 (round-15 winner): task-grouped + i-batched.
// Warp = (task t, 4 consecutive i); t: h = t/5, grp = t%5 -> 8 components.
// grid (NN/4, 15), block 256.
// ---------------------------------------------------------------------------
__global__ __launch_bounds__(256) void attn_out(
    const float* __restrict__ vc, const float* __restrict__ vpc,
    const __hip_bfloat16* __restrict__ A,
    float* __restrict__ cat, float* __restrict__ optb)
{
  const int w = threadIdx.x >> 6, lane = threadIdx.x & 63;
  const int t = blockIdx.y * 4 + w;
  const int h = t / 5, grp = t - h * 5;
  const int i0 = blockIdx.x * 4;

  const float* base = (grp < 2)
      ? vc + (size_t)(h * 16 + grp * 8) * NN
      : vpc + (size_t)(h * 24 + (grp - 2) * 8) * NN;
  const unsigned short* A0 = reinterpret_cast<const unsigned short*>(A)
                             + ((size_t)i0 * HH + h) * NN;
  const unsigned short* A1 = A0 + (size_t)HH * NN;
  const unsigned short* A2 = A1 + (size_t)HH * NN;
  const unsigned short* A3 = A2 + (size_t)HH * NN;

  float acc0[8], acc1[8], acc2[8], acc3[8];
#pragma unroll
  for (int r = 0; r < 8; r++) { acc0[r] = 0.f; acc1[r] = 0.f; acc2[r] = 0.f; acc3[r] = 0.f; }

#pragma unroll 2
  for (int it = 0; it < 16; it++) {
    const int j = it * 64 + lane;
    float vv[8];
#pragma unroll
    for (int r = 0; r < 8; r++) vv[r] = base[(size_t)r * NN + j];
    const float a0 = bf2f(A0[j]);
    const float a1 = bf2f(A1[j]);
    const float a2 = bf2f(A2[j]);
    const float a3 = bf2f(A3[j]);
#pragma unroll
    for (int r = 0; r < 8; r++) {
      acc0[r] += a0 * vv[r];
      acc1[r] += a1 * vv[r];
      acc2[r] += a2 * vv[r];
      acc3[r] += a3 * vv[r];
    }
  }
  for (int off = 32; off; off >>= 1) {
#pragma unroll
    for (int r = 0; r < 8; r++) {
      acc0[r] += __shfl_xor(acc0[r], off);
      acc1[r] += __shfl_xor(acc1[r], off);
      acc2[r] += __shfl_xor(acc2[r], off);
      acc3[r] += __shfl_xor(acc3[r], off);
    }
  }
  if (lane == 0) {
    if (grp < 2) {
      const int co = h * 16 + grp * 8;
      float* c0 = cat + (size_t)(i0 + 0) * DCAT + co;
      float* c1 = cat + (size_t)(i0 + 1) * DCAT + co;
      float* c2 = cat + (size_t)(i0 + 2) * DCAT + co;
      float* c3 = cat + (size_t)(i0 + 3) * DCAT + co;
#pragma unroll
      for (int r = 0; r < 8; r++) {
        c0[r] = acc0[r]; c1[r] = acc1[r]; c2[r] = acc2[r]; c3[r] = acc3[r];
      }
    } else {
      const int doff = (grp - 2) * 8;
      float* o0 = optb + ((size_t)(i0 + 0) * HH + h) * 24 + doff;
      float* o1 = optb + ((size_t)(i0 + 1) * HH + h) * 24 + doff;
      float* o2 = optb + ((size_t)(i0 + 2) * HH + h) * 24 + doff;
      float* o3 = optb + ((size_t)(i0 + 3) * HH + h) * 24 + doff;
#pragma unroll
      for (int r = 0; r < 8; r++) {
        o0[r] = acc0[r]; o1[r] = acc1[r]; o2[r] = acc2[r]; o3[r] = acc3[r];
      }
    }
  }
}

// ---------------------------------------------------------------------------
// opair_pass: split-j partial o_pair. grid (4, 1024). i reversed (L3 reuse).
// j-loop unrolled x8 -> 8 z loads in flight per thread.
// ---------------------------------------------------------------------------
__global__ __launch_bounds__(256) void opair_pass(
    const float* __restrict__ z, const __hip_bfloat16* __restrict__ A,
    float* __restrict__ partial)
{
  __shared__ float A_ls[256 * HH];  // 12 KB, [jloc][h]
  __shared__ float red[HH * CZ];    // 6 KB
  const int sp = blockIdx.x, i = NN - 1 - blockIdx.y;
  const int jb = sp * 256;
  const int tid = threadIdx.x;
  const int c4 = (tid & 31) * 4, jsub = tid >> 5;

  for (int e = tid; e < HH * 64; e += 256) {
    int h = e >> 6, j4 = (e & 63) * 4;
    ushort4 au = *reinterpret_cast<const ushort4*>(
        &A[((size_t)i * HH + h) * NN + jb + j4]);
    A_ls[(j4 + 0) * HH + h] = bf2f(au.x);
    A_ls[(j4 + 1) * HH + h] = bf2f(au.y);
    A_ls[(j4 + 2) * HH + h] = bf2f(au.z);
    A_ls[(j4 + 3) * HH + h] = bf2f(au.w);
  }
  for (int e = tid; e < HH * CZ; e += 256) red[e] = 0.f;
  __syncthreads();

  float4 acc[HH];
#pragma unroll
  for (int h = 0; h < HH; h++) acc[h] = make_float4(0.f, 0.f, 0.f, 0.f);

  const float* zrow = z + ((size_t)i * NN + jb + jsub * 32) * CZ + c4;
  const float* arow = &A_ls[jsub * 32 * HH];
  for (int j0 = 0; j0 < 32; j0 += 8) {
    float4 zq[8];
#pragma unroll
    for (int jj = 0; jj < 8; jj++)
      zq[jj] = *reinterpret_cast<const float4*>(&zrow[(size_t)(j0 + jj) * CZ]);
#pragma unroll
    for (int jj = 0; jj < 8; jj++) {
      const int j = j0 + jj;
      float4 a0 = *reinterpret_cast<const float4*>(&arow[j * HH]);
      float4 a1 = *reinterpret_cast<const float4*>(&arow[j * HH + 4]);
      float4 a2 = *reinterpret_cast<const float4*>(&arow[j * HH + 8]);
      acc[0].x += a0.x * zq[jj].x; acc[0].y += a0.x * zq[jj].y;
      acc[0].z += a0.x * zq[jj].z; acc[0].w += a0.x * zq[jj].w;
      acc[1].x += a0.y * zq[jj].x; acc[1].y += a0.y * zq[jj].y;
      acc[1].z += a0.y * zq[jj].z; acc[1].w += a0.y * zq[jj].w;
      acc[2].x += a0.z * zq[jj].x; acc[2].y += a0.z * zq[jj].y;
      acc[2].z += a0.z * zq[jj].z; acc[2].w += a0.z * zq[jj].w;
      acc[3].x += a0.w * zq[jj].x; acc[3].y += a0.w * zq[jj].y;
      acc[3].z += a0.w * zq[jj].z; acc[3].w += a0.w * zq[jj].w;
      acc[4].x += a1.x * zq[jj].x; acc[4].y += a1.x * zq[jj].y;
      acc[4].z += a1.x * zq[jj].z; acc[4].w += a1.x * zq[jj].w;
      acc[5].x += a1.y * zq[jj].x; acc[5].y += a1.y * zq[jj].y;
      acc[5].z += a1.y * zq[jj].z; acc[5].w += a1.y * zq[jj].w;
      acc[6].x += a1.z * zq[jj].x; acc[6].y += a1.z * zq[jj].y;
      acc[6].z += a1.z * zq[jj].z; acc[6].w += a1.z * zq[jj].w;
      acc[7].x += a1.w * zq[jj].x; acc[7].y += a1.w * zq[jj].y;
      acc[7].z += a1.w * zq[jj].z; acc[7].w += a1.w * zq[jj].w;
      acc[8].x += a2.x * zq[jj].x; acc[8].y += a2.x * zq[jj].y;
      acc[8].z += a2.x * zq[jj].z; acc[8].w += a2.x * zq[jj].w;
      acc[9].x += a2.y * zq[jj].x; acc[9].y += a2.y * zq[jj].y;
      acc[9].z += a2.y * zq[jj].z; acc[9].w += a2.y * zq[jj].w;
      acc[10].x += a2.z * zq[jj].x; acc[10].y += a2.z * zq[jj].y;
      acc[10].z += a2.z * zq[jj].z; acc[10].w += a2.z * zq[jj].w;
      acc[11].x += a2.w * zq[jj].x; acc[11].y += a2.w * zq[jj].y;
      acc[11].z += a2.w * zq[jj].z; acc[11].w += a2.w * zq[jj].w;
    }
  }
  for (int s = 0; s < 8; s++) {
    __syncthreads();
    if (jsub == s) {
#pragma unroll
      for (int h = 0; h < HH; h++) {
        red[h * CZ + c4 + 0] += acc[h].x;
        red[h * CZ + c4 + 1] += acc[h].y;
        red[h * CZ + c4 + 2] += acc[h].z;
        red[h * CZ + c4 + 3] += acc[h].w;
      }
    }
  }
  __syncthreads();
  float* pp = partial + ((size_t)(i * 4 + sp)) * (HH * CZ);
  for (int e = tid; e < HH * CZ; e += 256) pp[e] = red[e];
}

// ---------------------------------------------------------------------------
// opair_reduce (+fused finish): sum 4 partials -> cat[576:2112];
// inverse-rotate o_pt + norms -> cat[192:576]. grid NN, block 256.
// ---------------------------------------------------------------------------
__global__ __launch_bounds__(256) void opair_reduce(
    const float* __restrict__ partial, const float* __restrict__ optb,
    const float* __restrict__ rot, const float* __restrict__ trans,
    float* __restrict__ cat)
{
  const int i = blockIdx.x, tid = threadIdx.x;
  __shared__ float R_s[9], T_s[3];
  if (tid < 9) R_s[tid] = rot[i * 9 + tid];
  if (tid < 3) T_s[tid] = trans[i * 3 + tid];
  __syncthreads();

  const float* pp = partial + ((size_t)i * 4) * (HH * CZ);
  for (int e = tid; e < HH * CZ; e += 256) {
    float v = pp[e] + pp[HH * CZ + e] + pp[2 * HH * CZ + e] + pp[3 * HH * CZ + e];
    cat[(size_t)i * DCAT + 576 + e] = v;
  }
  if (tid < 96) {
    int h = tid >> 3, p = tid & 7;
    const float* ob = optb + ((size_t)i * HH + h) * 24 + p * 3;
    float gx = ob[0] - T_s[0];
    float gy = ob[1] - T_s[1];
    float gz = ob[2] - T_s[2];
    float lx = R_s[0] * gx + R_s[3] * gy + R_s[6] * gz;
    float ly = R_s[1] * gx + R_s[4] * gy + R_s[7] * gz;
    float lz = R_s[2] * gx + R_s[5] * gy + R_s[8] * gz;
    float* catr = cat + (size_t)i * DCAT;
    catr[192 + 0 * 96 + h * 8 + p] = lx;
    catr[192 + 1 * 96 + h * 8 + p] = ly;
    catr[192 + 2 * 96 + h * 8 + p] = lz;
    catr[480 + h * 8 + p] = sqrtf(lx * lx + ly * ly + lz * lz + 1e-8f);
  }
}

// ---------------------------------------------------------------------------
// out_gemm v3: out = cat @ wout + bout (1024 x 2112 x 384).
// 8 rows/block, K-tiled (OKT=528). grid (128, 3), block 256.
// ---------------------------------------------------------------------------
#define OKT 528
__global__ __launch_bounds__(256) void out_gemm(
    const float* __restrict__ cat, const float* __restrict__ wout,
    const float* __restrict__ bout, float* __restrict__ out)
{
  __shared__ float c_lds[8 * OKT];   // 16.9 KB
  const int n0 = blockIdx.x * 8;
  const int cq = blockIdx.y * 128 + (threadIdx.x & 31) * 4;
  const int rg = threadIdx.x >> 5;
  float a0 = 0.f, a1 = 0.f, a2 = 0.f, a3 = 0.f;

  for (int kc = 0; kc < DCAT / OKT; kc++) {
    __syncthreads();
    for (int idx = threadIdx.x; idx < 8 * OKT; idx += 256) {
      int r = idx / OKT, kk = idx - r * OKT;
      c_lds[idx] = cat[(size_t)(n0 + r) * DCAT + kc * OKT + kk];
    }
    __syncthreads();
    const float* crow = &c_lds[rg * OKT];
#pragma unroll 4
    for (int kk = 0; kk < OKT; kk++) {
      float cv = crow[kk];
      float4 w4 = *reinterpret_cast<const float4*>(
          &wout[(size_t)(kc * OKT + kk) * CS + cq]);
      a0 += cv * w4.x; a1 += cv * w4.y; a2 += cv * w4.z; a3 += cv * w4.w;
    }
  }
  float* o = out + (size_t)(n0 + rg) * CS + cq;
  o[0] = a0 + bout[cq]; o[1] = a1 + bout[cq + 1];
  o[2] = a2 + bout[cq + 2]; o[3] = a3 + bout[cq + 3];
}

// ---------------------------------------------------------------------------
extern "C" void kernel_launch(void* const* d_in, const int* in_sizes, int n_in,
                              void* d_out, int out_size, void* d_ws, size_t ws_size,
                              hipStream_t stream) {
  const float* s      = (const float*)d_in[0];
  const float* z      = (const float*)d_in[1];
  const float* rot    = (const float*)d_in[2];
  const float* trans  = (const float*)d_in[3];
  const float* mask   = (const float*)d_in[4];
  const float* wq     = (const float*)d_in[5];
  const float* bq     = (const float*)d_in[6];
  const float* wkv    = (const float*)d_in[7];
  const float* bkv    = (const float*)d_in[8];
  const float* wqp    = (const float*)d_in[9];
  const float* bqp    = (const float*)d_in[10];
  const float* wkvp   = (const float*)d_in[11];
  const float* bkvp   = (const float*)d_in[12];
  const float* wb     = (const float*)d_in[13];
  const float* bb     = (const float*)d_in[14];
  const float* head_w = (const float*)d_in[15];
  const float* wout   = (const float*)d_in[16];
  const float* bout   = (const float*)d_in[17];
  float* out = (float*)d_out;

  // workspace layout (floats; all bases 16-float aligned)
  float* ws = (float*)d_ws;
  float* proj_buf = ws;                                  // 1,179,648
  float* kc_buf   = proj_buf + (size_t)NN * PROJW;       // 196,608
  float* vc_buf   = kc_buf + (size_t)HH * 16 * NN;       // 196,608
  float* kpc_buf  = vc_buf + (size_t)HH * 16 * NN;       // 147,456
  float* vpc_buf  = kpc_buf + (size_t)HH * 12 * NN;      // 294,912
  float* knc_buf  = vpc_buf + (size_t)HH * 24 * NN;      // 12,288
  float* qpts_buf = knc_buf + (size_t)HH * NN;           // 147,456
  float* qn_buf   = qpts_buf + (size_t)NN * QPR;         // 12,288
  float* optb_buf = qn_buf + NN * HH + 16;               // 294,912
  float* cat_buf  = optb_buf + (size_t)NN * HH * 24;     // 2,162,688
  float* part_buf = cat_buf + (size_t)NN * DCAT;         // 6,291,456
  __hip_bfloat16* A_buf =
      (__hip_bfloat16*)(part_buf + (size_t)4 * NN * HH * CZ);  // 12,582,912 bf16

  proj_all<<<dim3(NN / 8, 9), dim3(256), 0, stream>>>(
      s, wq, bq, wkv, bkv, wqp, bqp, wkvp, bkvp, proj_buf);
  ipa_transform<<<dim3(NN), dim3(256), 0, stream>>>(
      proj_buf, rot, trans, kc_buf, vc_buf, qpts_buf, kpc_buf, vpc_buf,
      qn_buf, knc_buf);
  bias_pass<<<dim3(8, NN), dim3(256), 0, stream>>>(z, wb, A_buf);
  attn_logits<<<dim3(NN / 4, HH), dim3(256), 0, stream>>>(
      kc_buf, kpc_buf, knc_buf, proj_buf, qpts_buf, qn_buf,
      bb, head_w, mask, A_buf);
  attn_out<<<dim3(NN / 4, 15), dim3(256), 0, stream>>>(
      vc_buf, vpc_buf, A_buf, cat_buf, optb_buf);
  opair_pass<<<dim3(4, NN), dim3(256), 0, stream>>>(z, A_buf, part_buf);
  opair_reduce<<<dim3(NN), dim3(256), 0, stream>>>(
      part_buf, optb_buf, rot, trans, cat_buf);
  out_gemm<<<dim3(NN / 8, 3), dim3(256), 0, stream>>>(
      cat_buf, wout, bout, out);
}